// Round 4
// baseline (5207.909 us; speedup 1.0000x reference)
//
#include <hip/hip_runtime.h>
#include <hip/hip_bf16.h>
#include <math.h>

#define S 2048
#define E 1024
#define D 64
#define H 16

using bf16 = __hip_bfloat16;

__device__ __forceinline__ float b2f(bf16 v) { return __bfloat162float(v); }

// storage-type helpers (intermediates are fp32 or bf16 depending on ws_size)
__device__ __forceinline__ float ldf(const float* p, size_t i) { return p[i]; }
__device__ __forceinline__ float ldf(const bf16* p, size_t i) { return b2f(p[i]); }
__device__ __forceinline__ void  stf(float* p, size_t i, float v) { p[i] = v; }
__device__ __forceinline__ void  stf(bf16* p, size_t i, float v) { p[i] = __float2bfloat16(v); }

// ---------------------------------------------------------------------------
// Kernel 1: fused shared QKV projection + per-head linears.  (fp32 inputs)
// grid = S, block = 256.
// ---------------------------------------------------------------------------
template <typename T>
__global__ void qkv_head(const float* __restrict__ x,
                         const float* __restrict__ Wk,
                         const float* __restrict__ Wq,
                         const float* __restrict__ Wv,
                         const float* __restrict__ hWk, const float* __restrict__ hbk,
                         const float* __restrict__ hWv, const float* __restrict__ hbv,
                         const float* __restrict__ hWq, const float* __restrict__ hbq,
                         T* __restrict__ Kh, T* __restrict__ Qh, T* __restrict__ Vh) {
    const int s = blockIdx.x;
    const int t = threadIdx.x;  // 0..255

    __shared__ float xs[E];
    __shared__ float kv[3 * D];  // K,Q,V rows for this s

    for (int e = t; e < E; e += 256) xs[e] = x[(size_t)s * E + e];
    __syncthreads();

    if (t < 3 * D) {                       // 192 dot products of length E
        const int type = t >> 6;           // 0=K, 1=Q, 2=V
        const int d = t & 63;
        const float* W = ((type == 0) ? Wk : (type == 1) ? Wq : Wv) + (size_t)d * E;
        float acc = 0.f;
        for (int e = 0; e < E; ++e) acc += xs[e] * W[e];
        kv[type * D + d] = acc;
    }
    __syncthreads();

    // 3 * H * D = 3072 outputs, 12 per thread
    for (int o = t; o < 3 * H * D; o += 256) {
        const int type = o >> 10;          // 0=K, 1=Q, 2=V
        const int idx = o & 1023;
        const int h = idx >> 6, e2 = idx & 63;
        const float* W = ((type == 0) ? hWk : (type == 1) ? hWq : hWv) + ((size_t)h * D + e2) * D;
        const float* b = (type == 0) ? hbk : (type == 1) ? hbq : hbv;
        const float* in = kv + type * D;
        float acc = b[h * D + e2];
        for (int d = 0; d < D; ++d) acc += in[d] * W[d];
        T* out = (type == 0) ? Kh : (type == 1) ? Qh : Vh;
        stf(out, ((size_t)h * S + s) * D + e2, acc);
    }
}

// ---------------------------------------------------------------------------
// Kernel 2: attention for one (h, q) row. Scores row lives in LDS (8 KB).
// Writes O directly in concat layout cat[q, h*D + d].
// grid = (S, H), block = 256.
// ---------------------------------------------------------------------------
template <typename T>
__global__ void attn_row(const T* __restrict__ Qh,
                         const T* __restrict__ Kh,
                         const T* __restrict__ Vh,
                         T* __restrict__ cat) {
    const int q = blockIdx.x;
    const int h = blockIdx.y;
    const int t = threadIdx.x;  // 0..255

    __shared__ float qsh[D];
    __shared__ float sc[S];
    __shared__ float red[256];

    if (t < D) qsh[t] = ldf(Qh, ((size_t)h * S + q) * D + t);
    __syncthreads();

    const float scale = 0.125f;  // 1/sqrt(64)

    float lmax = -INFINITY;
    for (int k = t; k < S; k += 256) {
        const size_t base = ((size_t)h * S + k) * D;
        float acc = 0.f;
        for (int d = 0; d < D; ++d) acc += qsh[d] * ldf(Kh, base + d);
        acc *= scale;
        sc[k] = acc;
        lmax = fmaxf(lmax, acc);
    }
    red[t] = lmax;
    __syncthreads();
    for (int w = 128; w > 0; w >>= 1) {
        if (t < w) red[t] = fmaxf(red[t], red[t + w]);
        __syncthreads();
    }
    const float m = red[0];
    __syncthreads();

    float lsum = 0.f;
    for (int k = t; k < S; k += 256) {
        float p = __expf(sc[k] - m);
        sc[k] = p;
        lsum += p;
    }
    red[t] = lsum;
    __syncthreads();
    for (int w = 128; w > 0; w >>= 1) {
        if (t < w) red[t] += red[t + w];
        __syncthreads();
    }
    const float inv = 1.f / red[0];

    // O[d] = sum_k p_k * V[k,d]; thread t: d = t&63, k-chunk = t>>6
    const int d = t & 63, c = t >> 6;
    float acc = 0.f;
    const int k0 = c * (S / 4), k1 = k0 + (S / 4);
    for (int k = k0; k < k1; ++k) acc += sc[k] * ldf(Vh, ((size_t)h * S + k) * D + d);
    __syncthreads();  // all reads of red[0]/sc complete before red is overwritten
    red[t] = acc;
    __syncthreads();
    if (t < 64) {
        float o = (red[t] + red[t + 64] + red[t + 128] + red[t + 192]) * inv;
        stf(cat, (size_t)q * E + h * D + d, o);
    }
}

// ---------------------------------------------------------------------------
// Kernel 3: fused output projection + residual + LayerNorm -> fp32 out.
// grid = S, block = 256. y-row stays in LDS; no ypre buffer.
// ---------------------------------------------------------------------------
template <typename T>
__global__ void out_ln(const T* __restrict__ cat,
                       const float* __restrict__ Wo,
                       const float* __restrict__ bo,
                       const float* __restrict__ x,
                       const float* __restrict__ gamma,
                       const float* __restrict__ beta,
                       float* __restrict__ out) {
    const int s = blockIdx.x;
    const int t = threadIdx.x;

    __shared__ float csh[E];
    __shared__ float yrow[E];
    __shared__ float red[256];

    for (int f = t; f < E; f += 256) csh[f] = ldf(cat, (size_t)s * E + f);
    __syncthreads();

    float lsum = 0.f;
    for (int e = t; e < E; e += 256) {
        const float* wr = Wo + (size_t)e * E;
        float acc = 0.f;
        for (int f = 0; f < E; ++f) acc += csh[f] * wr[f];
        float y = acc + bo[e] + x[(size_t)s * E + e];
        yrow[e] = y;
        lsum += y;
    }
    red[t] = lsum;
    __syncthreads();
    for (int w = 128; w > 0; w >>= 1) {
        if (t < w) red[t] += red[t + w];
        __syncthreads();
    }
    const float mu = red[0] * (1.f / E);
    __syncthreads();

    float lv = 0.f;
    for (int e = t; e < E; e += 256) {
        float dd = yrow[e] - mu;
        lv += dd * dd;
    }
    red[t] = lv;
    __syncthreads();
    for (int w = 128; w > 0; w >>= 1) {
        if (t < w) red[t] += red[t + w];
        __syncthreads();
    }
    const float rstd = rsqrtf(red[0] * (1.f / E) + 1e-5f);

    for (int e = t; e < E; e += 256) {
        out[(size_t)s * E + e] = (yrow[e] - mu) * rstd * gamma[e] + beta[e];
    }
}

// ---------------------------------------------------------------------------
template <typename T>
static void launch_all(const float* x, const float* Wk, const float* Wq, const float* Wv,
                       const float* hWk, const float* hbk, const float* hWv, const float* hbv,
                       const float* hWq, const float* hbq, const float* Wo, const float* bo,
                       const float* gamma, const float* beta, float* out,
                       T* ws, hipStream_t stream) {
    const size_t HSD = (size_t)H * S * D;  // 2097152
    T* Kh  = ws;
    T* Qh  = Kh + HSD;
    T* Vh  = Qh + HSD;
    T* cat = Vh + HSD;

    qkv_head<T><<<S, 256, 0, stream>>>(x, Wk, Wq, Wv, hWk, hbk, hWv, hbv, hWq, hbq,
                                       Kh, Qh, Vh);
    attn_row<T><<<dim3(S, H), 256, 0, stream>>>(Qh, Kh, Vh, cat);
    out_ln<T><<<S, 256, 0, stream>>>(cat, Wo, bo, x, gamma, beta, out);
}

extern "C" void kernel_launch(void* const* d_in, const int* in_sizes, int n_in,
                              void* d_out, int out_size, void* d_ws, size_t ws_size,
                              hipStream_t stream) {
    const float* x     = (const float*)d_in[0];
    const float* Wk    = (const float*)d_in[1];
    const float* Wq    = (const float*)d_in[2];
    const float* Wv    = (const float*)d_in[3];
    const float* hWk   = (const float*)d_in[4];
    const float* hbk   = (const float*)d_in[5];
    const float* hWv   = (const float*)d_in[6];
    const float* hbv   = (const float*)d_in[7];
    const float* hWq   = (const float*)d_in[8];
    const float* hbq   = (const float*)d_in[9];
    const float* Wo    = (const float*)d_in[10];
    const float* bo    = (const float*)d_in[11];
    const float* gamma = (const float*)d_in[12];
    const float* beta  = (const float*)d_in[13];
    float* out = (float*)d_out;

    const size_t need_elems = 4ull * H * S * D;  // Kh,Qh,Vh,cat (2M elems each)

    // ws_size is fixed per process -> identical branch every call (capture-safe).
    if (ws_size >= need_elems * sizeof(float)) {
        launch_all<float>(x, Wk, Wq, Wv, hWk, hbk, hWv, hbv, hWq, hbq, Wo, bo,
                          gamma, beta, out, (float*)d_ws, stream);
    } else {
        launch_all<bf16>(x, Wk, Wq, Wv, hWk, hbk, hWv, hbv, hWq, hbq, Wo, bo,
                         gamma, beta, out, (bf16*)d_ws, stream);
    }
}

// Round 5
// 2666.972 us; speedup vs baseline: 1.9527x; 1.9527x over previous
//
#include <hip/hip_runtime.h>
#include <hip/hip_bf16.h>
#include <math.h>

#define S 2048
#define E 1024
#define D 64
#define H 16

using bf16 = __hip_bfloat16;
typedef short v8s __attribute__((ext_vector_type(8)));   // 8 bf16 (4 VGPRs) — per guide §3
typedef float v4f __attribute__((ext_vector_type(4)));

__device__ __forceinline__ float b2f(bf16 v) { return __bfloat162float(v); }

// ---------------------------------------------------------------------------
// Kernel 1: fused shared QKV projection + per-head linears. fp32 in, bf16 out.
// grid = S, block = 256.
// ---------------------------------------------------------------------------
__global__ void qkv_head(const float* __restrict__ x,
                         const float* __restrict__ Wk,
                         const float* __restrict__ Wq,
                         const float* __restrict__ Wv,
                         const float* __restrict__ hWk, const float* __restrict__ hbk,
                         const float* __restrict__ hWv, const float* __restrict__ hbv,
                         const float* __restrict__ hWq, const float* __restrict__ hbq,
                         bf16* __restrict__ Kh, bf16* __restrict__ Qh, bf16* __restrict__ Vh) {
    const int s = blockIdx.x;
    const int t = threadIdx.x;  // 0..255

    __shared__ float xs[E];
    __shared__ float kv[3 * D];

    {
        const v4f* xr = (const v4f*)(x + (size_t)s * E);
        v4f* xd = (v4f*)xs;
        for (int i = t; i < E / 4; i += 256) xd[i] = xr[i];
    }
    __syncthreads();

    if (t < 3 * D) {                       // 192 dots of length E, float4 + 4 chains
        const int type = t >> 6;           // 0=K, 1=Q, 2=V
        const int d = t & 63;
        const float* W = ((type == 0) ? Wk : (type == 1) ? Wq : Wv) + (size_t)d * E;
        const v4f* w4 = (const v4f*)W;
        const v4f* x4 = (const v4f*)xs;
        v4f a = {0.f, 0.f, 0.f, 0.f};
        for (int i = 0; i < E / 4; ++i) a += x4[i] * w4[i];
        kv[type * D + d] = a[0] + a[1] + a[2] + a[3];
    }
    __syncthreads();

    // 3 * H * D = 3072 outputs, 12 per thread
    for (int o = t; o < 3 * H * D; o += 256) {
        const int type = o >> 10;          // 0=K, 1=Q, 2=V
        const int idx = o & 1023;
        const int h = idx >> 6, e2 = idx & 63;
        const float* W = ((type == 0) ? hWk : (type == 1) ? hWq : hWv) + ((size_t)h * D + e2) * D;
        const float* b = (type == 0) ? hbk : (type == 1) ? hbq : hbv;
        const float* in = kv + type * D;
        float acc = b[h * D + e2];
        for (int d = 0; d < D; ++d) acc += in[d] * W[d];
        bf16* outp = (type == 0) ? Kh : (type == 1) ? Qh : Vh;
        outp[((size_t)h * S + s) * D + e2] = __float2bfloat16(acc);
    }
}

// ---------------------------------------------------------------------------
// Kernel 2: MFMA flash attention. One block = 1 head x 64 q-rows (4 waves x 16).
// K-tiles of 32 keys staged in LDS; online softmax; P LDS round-trip (C->A).
// grid = (S/64, H), block = 256.
// LDS row strides are multiples of 8 elems (16 B) for aligned ds_read_b128,
// and chosen so b128 bank aliasing is <=2-way (free).
// ---------------------------------------------------------------------------
#define TQ 64
#define TK 32
#define KPAD 72   // K tile row stride (elems):  144 B
#define VPAD 40   // Vt row stride:              80 B
#define PPAD 40   // P row stride:               80 B

__global__ void attn_mfma(const bf16* __restrict__ Qh,
                          const bf16* __restrict__ Kh,
                          const bf16* __restrict__ Vh,
                          bf16* __restrict__ cat) {
    const int h = blockIdx.y;
    const int q0 = blockIdx.x * TQ;
    const int t = threadIdx.x;
    const int wave = t >> 6, lane = t & 63;
    const int quad = lane >> 4, l16 = lane & 15;

    __shared__ bf16 Kt[TK][KPAD];        // [key][d]
    __shared__ bf16 Vt[D][VPAD];         // [d][key]  (transposed V tile)
    __shared__ bf16 Pt[4][16][PPAD];     // per-wave P [q-row][key]

    // Q fragments (A-layout: lane&15 = q-row, quad*8+j = k), 2 k-steps of 32
    const int qrow = q0 + wave * 16 + l16;
    v8s qf[2];
    {
        const v8s* qp = (const v8s*)(Qh + ((size_t)h * S + qrow) * D);
        qf[0] = qp[quad];        // k = quad*8 + [0..7]
        qf[1] = qp[quad + 4];    // k = 32 + quad*8 + [0..7]
    }

    v4f oc[4] = {{0,0,0,0},{0,0,0,0},{0,0,0,0},{0,0,0,0}};
    float m_run[4], l_run[4];
#pragma unroll
    for (int r = 0; r < 4; ++r) { m_run[r] = -INFINITY; l_run[r] = 0.f; }

    const float scale = 0.125f * 1.44269504f;  // 1/sqrt(D) * log2(e); softmax in base-2

    for (int k0 = 0; k0 < S; k0 += TK) {
        __syncthreads();  // prior iteration's compute done before re-staging
        {
            // stage K tile: thread t -> row t>>3, cols (t&7)*8 .. +7
            const int r = t >> 3, c = (t & 7) * 8;
            *(v8s*)&Kt[r][c] = *(const v8s*)(Kh + ((size_t)h * S + k0 + r) * D + c);
            // stage V transposed: load 8 consecutive d's of one key, scatter to Vt[d][key]
            const int key = r, d0 = c;
            v8s vv = *(const v8s*)(Vh + ((size_t)h * S + k0 + key) * D + d0);
            const bf16* vb = (const bf16*)&vv;
#pragma unroll
            for (int j = 0; j < 8; ++j) Vt[d0 + j][key] = vb[j];
        }
        __syncthreads();

        // QK^T: P(16 x 32) in two C frags (cols 0-15, 16-31)
        v4f sc0 = {0,0,0,0}, sc1 = {0,0,0,0};
#pragma unroll
        for (int ks = 0; ks < 2; ++ks) {
            v8s kf0 = *(const v8s*)&Kt[l16][quad * 8 + ks * 32];
            v8s kf1 = *(const v8s*)&Kt[l16 + 16][quad * 8 + ks * 32];
            sc0 = __builtin_amdgcn_mfma_f32_16x16x32_bf16(qf[ks], kf0, sc0, 0, 0, 0);
            sc1 = __builtin_amdgcn_mfma_f32_16x16x32_bf16(qf[ks], kf1, sc1, 0, 0, 0);
        }

        // online softmax; C layout: row = quad*4+r, col = l16 (+16 for sc1)
#pragma unroll
        for (int r = 0; r < 4; ++r) {
            float a = sc0[r] * scale, b = sc1[r] * scale;
            float v = fmaxf(a, b);
            v = fmaxf(v, __shfl_xor(v, 1, 16));
            v = fmaxf(v, __shfl_xor(v, 2, 16));
            v = fmaxf(v, __shfl_xor(v, 4, 16));
            v = fmaxf(v, __shfl_xor(v, 8, 16));
            const float mnew = fmaxf(m_run[r], v);
            const float p0 = exp2f(a - mnew);
            const float p1 = exp2f(b - mnew);
            float sum = p0 + p1;
            sum += __shfl_xor(sum, 1, 16);
            sum += __shfl_xor(sum, 2, 16);
            sum += __shfl_xor(sum, 4, 16);
            sum += __shfl_xor(sum, 8, 16);
            const float alpha = exp2f(m_run[r] - mnew);  // first iter: exp2(-inf)=0
            l_run[r] = l_run[r] * alpha + sum;
            m_run[r] = mnew;
#pragma unroll
            for (int nt = 0; nt < 4; ++nt) oc[nt][r] *= alpha;
            Pt[wave][quad * 4 + r][l16]      = __float2bfloat16(p0);
            Pt[wave][quad * 4 + r][l16 + 16] = __float2bfloat16(p1);
        }
        __syncthreads();  // P visible (and keeps Kt/Vt barrier pattern intact)

        // PV: O(16 x 64) += P(16 x 32) @ V(32 x 64), 4 n-tiles of 16
        v8s pf = *(const v8s*)&Pt[wave][l16][quad * 8];   // A-layout
#pragma unroll
        for (int nt = 0; nt < 4; ++nt) {
            v8s vf = *(const v8s*)&Vt[nt * 16 + l16][quad * 8];  // B-layout
            oc[nt] = __builtin_amdgcn_mfma_f32_16x16x32_bf16(pf, vf, oc[nt], 0, 0, 0);
        }
    }

    // epilogue: C layout row = quad*4+r, col = nt*16+l16; divide by l, store bf16
#pragma unroll
    for (int r = 0; r < 4; ++r) {
        const float invl = 1.f / l_run[r];
        const int qg = q0 + wave * 16 + quad * 4 + r;
        bf16* crow = cat + (size_t)qg * E + h * D;
#pragma unroll
        for (int nt = 0; nt < 4; ++nt)
            crow[nt * 16 + l16] = __float2bfloat16(oc[nt][r] * invl);
    }
}

// ---------------------------------------------------------------------------
// Kernel 3: fused output projection + residual + LayerNorm -> fp32 out.
// grid = S, block = 256; thread t owns e in {t, t+256, t+512, t+768}.
// ---------------------------------------------------------------------------
__global__ void out_ln(const bf16* __restrict__ cat,
                       const float* __restrict__ Wo,
                       const float* __restrict__ bo,
                       const float* __restrict__ x,
                       const float* __restrict__ gamma,
                       const float* __restrict__ beta,
                       float* __restrict__ out) {
    const int s = blockIdx.x;
    const int t = threadIdx.x;

    __shared__ float csh[E];
    __shared__ float red[256];

    for (int f = t; f < E; f += 256) csh[f] = b2f(cat[(size_t)s * E + f]);
    __syncthreads();

    v4f acc[4] = {{0,0,0,0},{0,0,0,0},{0,0,0,0},{0,0,0,0}};
    const float* w[4];
#pragma unroll
    for (int i = 0; i < 4; ++i) w[i] = Wo + (size_t)(t + i * 256) * E;
    for (int f = 0; f < E; f += 4) {
        v4f c = *(const v4f*)&csh[f];
#pragma unroll
        for (int i = 0; i < 4; ++i) acc[i] += c * *(const v4f*)&w[i][f];
    }

    float yv[4];
    float lsum = 0.f;
#pragma unroll
    for (int i = 0; i < 4; ++i) {
        const int e = t + i * 256;
        float y = acc[i][0] + acc[i][1] + acc[i][2] + acc[i][3]
                + bo[e] + x[(size_t)s * E + e];
        yv[i] = y;
        lsum += y;
    }
    red[t] = lsum;
    __syncthreads();
    for (int w2 = 128; w2 > 0; w2 >>= 1) {
        if (t < w2) red[t] += red[t + w2];
        __syncthreads();
    }
    const float mu = red[0] * (1.f / E);
    __syncthreads();

    float lv = 0.f;
#pragma unroll
    for (int i = 0; i < 4; ++i) { float dd = yv[i] - mu; lv += dd * dd; }
    red[t] = lv;
    __syncthreads();
    for (int w2 = 128; w2 > 0; w2 >>= 1) {
        if (t < w2) red[t] += red[t + w2];
        __syncthreads();
    }
    const float rstd = rsqrtf(red[0] * (1.f / E) + 1e-5f);

#pragma unroll
    for (int i = 0; i < 4; ++i) {
        const int e = t + i * 256;
        out[(size_t)s * E + e] = (yv[i] - mu) * rstd * gamma[e] + beta[e];
    }
}

// ---------------------------------------------------------------------------
extern "C" void kernel_launch(void* const* d_in, const int* in_sizes, int n_in,
                              void* d_out, int out_size, void* d_ws, size_t ws_size,
                              hipStream_t stream) {
    const float* x     = (const float*)d_in[0];
    const float* Wk    = (const float*)d_in[1];
    const float* Wq    = (const float*)d_in[2];
    const float* Wv    = (const float*)d_in[3];
    const float* hWk   = (const float*)d_in[4];
    const float* hbk   = (const float*)d_in[5];
    const float* hWv   = (const float*)d_in[6];
    const float* hbv   = (const float*)d_in[7];
    const float* hWq   = (const float*)d_in[8];
    const float* hbq   = (const float*)d_in[9];
    const float* Wo    = (const float*)d_in[10];
    const float* bo    = (const float*)d_in[11];
    const float* gamma = (const float*)d_in[12];
    const float* beta  = (const float*)d_in[13];
    float* out = (float*)d_out;

    // bf16 workspace: Kh,Qh,Vh,cat = 4 x 2M elems x 2 B = 16 MB (proven available)
    bf16* ws  = (bf16*)d_ws;
    const size_t HSD = (size_t)H * S * D;  // 2097152
    bf16* Kh  = ws;
    bf16* Qh  = Kh + HSD;
    bf16* Vh  = Qh + HSD;
    bf16* cat = Vh + HSD;

    qkv_head<<<S, 256, 0, stream>>>(x, Wk, Wq, Wv, hWk, hbk, hWv, hbv, hWq, hbq,
                                    Kh, Qh, Vh);
    attn_mfma<<<dim3(S / TQ, H), 256, 0, stream>>>(Qh, Kh, Vh, cat);
    out_ln<<<S, 256, 0, stream>>>(cat, Wo, bo, x, gamma, beta, out);
}

// Round 6
// 755.998 us; speedup vs baseline: 6.8888x; 3.5278x over previous
//
#include <hip/hip_runtime.h>
#include <hip/hip_bf16.h>
#include <math.h>

#define S 2048
#define E 1024
#define D 64
#define H 16

using f16 = _Float16;
typedef _Float16 v8h __attribute__((ext_vector_type(8)));  // 8 fp16 (4 VGPRs)
typedef _Float16 v4h __attribute__((ext_vector_type(4)));
typedef float v4f __attribute__((ext_vector_type(4)));

// ---------------------------------------------------------------------------
// Kernel 0: Wo fp32 -> fp16 (row-major [e][f] preserved)
// ---------------------------------------------------------------------------
__global__ void wo_convert(const float* __restrict__ Wo, f16* __restrict__ WoB) {
    const size_t i = (size_t)blockIdx.x * 256 + threadIdx.x;  // 1 v4f per thread
    v4f w = ((const v4f*)Wo)[i];
    v4h h = {(f16)w[0], (f16)w[1], (f16)w[2], (f16)w[3]};
    ((v4h*)WoB)[i] = h;
}

// ---------------------------------------------------------------------------
// Kernel 1: fused shared QKV projection + per-head linears. fp32 in, fp16 out.
// grid = S, block = 256.
// ---------------------------------------------------------------------------
__global__ void qkv_head(const float* __restrict__ x,
                         const float* __restrict__ Wk,
                         const float* __restrict__ Wq,
                         const float* __restrict__ Wv,
                         const float* __restrict__ hWk, const float* __restrict__ hbk,
                         const float* __restrict__ hWv, const float* __restrict__ hbv,
                         const float* __restrict__ hWq, const float* __restrict__ hbq,
                         f16* __restrict__ Kh, f16* __restrict__ Qh, f16* __restrict__ Vh) {
    const int s = blockIdx.x;
    const int t = threadIdx.x;  // 0..255

    __shared__ float xs[E];
    __shared__ float kv[3 * D];

    {
        const v4f* xr = (const v4f*)(x + (size_t)s * E);
        v4f* xd = (v4f*)xs;
        for (int i = t; i < E / 4; i += 256) xd[i] = xr[i];
    }
    __syncthreads();

    if (t < 3 * D) {                       // 192 dots of length E
        const int type = t >> 6;           // 0=K, 1=Q, 2=V
        const int d = t & 63;
        const float* W = ((type == 0) ? Wk : (type == 1) ? Wq : Wv) + (size_t)d * E;
        const v4f* w4 = (const v4f*)W;
        const v4f* x4 = (const v4f*)xs;
        v4f a = {0.f, 0.f, 0.f, 0.f};
        for (int i = 0; i < E / 4; ++i) a += x4[i] * w4[i];
        kv[type * D + d] = a[0] + a[1] + a[2] + a[3];
    }
    __syncthreads();

    for (int o = t; o < 3 * H * D; o += 256) {
        const int type = o >> 10;          // 0=K, 1=Q, 2=V
        const int idx = o & 1023;
        const int h = idx >> 6, e2 = idx & 63;
        const float* W = ((type == 0) ? hWk : (type == 1) ? hWq : hWv) + ((size_t)h * D + e2) * D;
        const float* b = (type == 0) ? hbk : (type == 1) ? hbq : hbv;
        const float* in = kv + type * D;
        float acc = b[h * D + e2];
        for (int d = 0; d < D; ++d) acc += in[d] * W[d];
        f16* outp = (type == 0) ? Kh : (type == 1) ? Qh : Vh;
        outp[((size_t)h * S + s) * D + e2] = (f16)acc;
    }
}

// ---------------------------------------------------------------------------
// Kernel 2: MFMA flash attention (fp16). One block = 1 head x 64 q-rows.
// grid = (S/64, H), block = 256.
// ---------------------------------------------------------------------------
#define TQ 64
#define TK 32
#define KPAD 72
#define VPAD 40
#define PPAD 40

__global__ void attn_mfma(const f16* __restrict__ Qh,
                          const f16* __restrict__ Kh,
                          const f16* __restrict__ Vh,
                          f16* __restrict__ cat) {
    const int h = blockIdx.y;
    const int q0 = blockIdx.x * TQ;
    const int t = threadIdx.x;
    const int wave = t >> 6, lane = t & 63;
    const int quad = lane >> 4, l16 = lane & 15;

    __shared__ f16 Kt[TK][KPAD];        // [key][d]
    __shared__ f16 Vt[D][VPAD];         // [d][key]
    __shared__ f16 Pt[4][16][PPAD];     // per-wave P [q-row][key]

    const int qrow = q0 + wave * 16 + l16;
    v8h qf[2];
    {
        const v8h* qp = (const v8h*)(Qh + ((size_t)h * S + qrow) * D);
        qf[0] = qp[quad];
        qf[1] = qp[quad + 4];
    }

    v4f oc[4] = {{0,0,0,0},{0,0,0,0},{0,0,0,0},{0,0,0,0}};
    float m_run[4], l_run[4];
#pragma unroll
    for (int r = 0; r < 4; ++r) { m_run[r] = -INFINITY; l_run[r] = 0.f; }

    const float scale = 0.125f * 1.44269504f;  // 1/sqrt(D) * log2(e)

    for (int k0 = 0; k0 < S; k0 += TK) {
        __syncthreads();
        {
            const int r = t >> 3, c = (t & 7) * 8;
            *(v8h*)&Kt[r][c] = *(const v8h*)(Kh + ((size_t)h * S + k0 + r) * D + c);
            v8h vv = *(const v8h*)(Vh + ((size_t)h * S + k0 + r) * D + c);
#pragma unroll
            for (int j = 0; j < 8; ++j) Vt[c + j][r] = vv[j];
        }
        __syncthreads();

        v4f sc0 = {0,0,0,0}, sc1 = {0,0,0,0};
#pragma unroll
        for (int ks = 0; ks < 2; ++ks) {
            v8h kf0 = *(const v8h*)&Kt[l16][quad * 8 + ks * 32];
            v8h kf1 = *(const v8h*)&Kt[l16 + 16][quad * 8 + ks * 32];
            sc0 = __builtin_amdgcn_mfma_f32_16x16x32_f16(qf[ks], kf0, sc0, 0, 0, 0);
            sc1 = __builtin_amdgcn_mfma_f32_16x16x32_f16(qf[ks], kf1, sc1, 0, 0, 0);
        }

#pragma unroll
        for (int r = 0; r < 4; ++r) {
            float a = sc0[r] * scale, b = sc1[r] * scale;
            float v = fmaxf(a, b);
            v = fmaxf(v, __shfl_xor(v, 1, 16));
            v = fmaxf(v, __shfl_xor(v, 2, 16));
            v = fmaxf(v, __shfl_xor(v, 4, 16));
            v = fmaxf(v, __shfl_xor(v, 8, 16));
            const float mnew = fmaxf(m_run[r], v);
            const float p0 = exp2f(a - mnew);
            const float p1 = exp2f(b - mnew);
            float sum = p0 + p1;
            sum += __shfl_xor(sum, 1, 16);
            sum += __shfl_xor(sum, 2, 16);
            sum += __shfl_xor(sum, 4, 16);
            sum += __shfl_xor(sum, 8, 16);
            const float alpha = exp2f(m_run[r] - mnew);
            l_run[r] = l_run[r] * alpha + sum;
            m_run[r] = mnew;
#pragma unroll
            for (int nt = 0; nt < 4; ++nt) oc[nt][r] *= alpha;
            Pt[wave][quad * 4 + r][l16]      = (f16)p0;
            Pt[wave][quad * 4 + r][l16 + 16] = (f16)p1;
        }
        __syncthreads();

        v8h pf = *(const v8h*)&Pt[wave][l16][quad * 8];
#pragma unroll
        for (int nt = 0; nt < 4; ++nt) {
            v8h vf = *(const v8h*)&Vt[nt * 16 + l16][quad * 8];
            oc[nt] = __builtin_amdgcn_mfma_f32_16x16x32_f16(pf, vf, oc[nt], 0, 0, 0);
        }
    }

#pragma unroll
    for (int r = 0; r < 4; ++r) {
        const float invl = 1.f / l_run[r];
        const int qg = q0 + wave * 16 + quad * 4 + r;
        f16* crow = cat + (size_t)qg * E + h * D;
#pragma unroll
        for (int nt = 0; nt < 4; ++nt)
            crow[nt * 16 + l16] = (f16)(oc[nt][r] * invl);
    }
}

// ---------------------------------------------------------------------------
// Kernel 3: MFMA GEMM  y[s,e] = cat[s,:]·WoB[e,:] + bo[e] + x[s,e]  (fp32 y)
// tile 64x64, block = 256 (4 waves: wave = 16 m-rows x 64 n-cols).
// grid = (S/64, E/64).
// ---------------------------------------------------------------------------
#define GPAD 40

__global__ void gemm_y(const f16* __restrict__ cat,
                       const f16* __restrict__ WoB,
                       const float* __restrict__ bo,
                       const float* __restrict__ x,
                       float* __restrict__ y) {
    const int m0 = blockIdx.x * 64;
    const int n0 = blockIdx.y * 64;
    const int t = threadIdx.x;
    const int wave = t >> 6, lane = t & 63;
    const int quad = lane >> 4, l16 = lane & 15;

    __shared__ f16 At[64][GPAD];
    __shared__ f16 Bt[64][GPAD];

    v4f acc[4] = {{0,0,0,0},{0,0,0,0},{0,0,0,0},{0,0,0,0}};

    const int sr = t >> 2, sc = (t & 3) * 8;  // staging: row, col-8
    for (int k0 = 0; k0 < E; k0 += 32) {
        __syncthreads();
        *(v8h*)&At[sr][sc] = *(const v8h*)(cat + (size_t)(m0 + sr) * E + k0 + sc);
        *(v8h*)&Bt[sr][sc] = *(const v8h*)(WoB + (size_t)(n0 + sr) * E + k0 + sc);
        __syncthreads();

        v8h af = *(const v8h*)&At[wave * 16 + l16][quad * 8];
#pragma unroll
        for (int nt = 0; nt < 4; ++nt) {
            v8h bf = *(const v8h*)&Bt[nt * 16 + l16][quad * 8];
            acc[nt] = __builtin_amdgcn_mfma_f32_16x16x32_f16(af, bf, acc[nt], 0, 0, 0);
        }
    }

#pragma unroll
    for (int r = 0; r < 4; ++r) {
        const int m = m0 + wave * 16 + quad * 4 + r;
#pragma unroll
        for (int nt = 0; nt < 4; ++nt) {
            const int e = n0 + nt * 16 + l16;
            y[(size_t)m * E + e] = acc[nt][r] + bo[e] + x[(size_t)m * E + e];
        }
    }
}

// ---------------------------------------------------------------------------
// Kernel 4: LayerNorm rows of y -> fp32 out. grid = S, block = 256.
// ---------------------------------------------------------------------------
__global__ void ln(const float* __restrict__ y,
                   const float* __restrict__ gamma,
                   const float* __restrict__ beta,
                   float* __restrict__ out) {
    const int s = blockIdx.x;
    const int t = threadIdx.x;
    __shared__ float red[256];

    float yv[4];
    float lsum = 0.f;
#pragma unroll
    for (int i = 0; i < 4; ++i) {
        yv[i] = y[(size_t)s * E + t + i * 256];
        lsum += yv[i];
    }
    red[t] = lsum;
    __syncthreads();
    for (int w = 128; w > 0; w >>= 1) {
        if (t < w) red[t] += red[t + w];
        __syncthreads();
    }
    const float mu = red[0] * (1.f / E);
    __syncthreads();

    float lv = 0.f;
#pragma unroll
    for (int i = 0; i < 4; ++i) { float dd = yv[i] - mu; lv += dd * dd; }
    red[t] = lv;
    __syncthreads();
    for (int w = 128; w > 0; w >>= 1) {
        if (t < w) red[t] += red[t + w];
        __syncthreads();
    }
    const float rstd = rsqrtf(red[0] * (1.f / E) + 1e-5f);

#pragma unroll
    for (int i = 0; i < 4; ++i) {
        const int e = t + i * 256;
        out[(size_t)s * E + e] = (yv[i] - mu) * rstd * gamma[e] + beta[e];
    }
}

// ---------------------------------------------------------------------------
extern "C" void kernel_launch(void* const* d_in, const int* in_sizes, int n_in,
                              void* d_out, int out_size, void* d_ws, size_t ws_size,
                              hipStream_t stream) {
    const float* x     = (const float*)d_in[0];
    const float* Wk    = (const float*)d_in[1];
    const float* Wq    = (const float*)d_in[2];
    const float* Wv    = (const float*)d_in[3];
    const float* hWk   = (const float*)d_in[4];
    const float* hbk   = (const float*)d_in[5];
    const float* hWv   = (const float*)d_in[6];
    const float* hbv   = (const float*)d_in[7];
    const float* hWq   = (const float*)d_in[8];
    const float* hbq   = (const float*)d_in[9];
    const float* Wo    = (const float*)d_in[10];
    const float* bo    = (const float*)d_in[11];
    const float* gamma = (const float*)d_in[12];
    const float* beta  = (const float*)d_in[13];
    float* out = (float*)d_out;

    // ws layout (bytes): Kh 4M | Qh 4M | Vh 4M | cat 4M | WoB 2M | y 8M = 26 MB
    char* base = (char*)d_ws;
    const size_t HSD = (size_t)H * S * D;      // 2097152 elems
    f16* Kh  = (f16*)(base);
    f16* Qh  = (f16*)(base + 4  * (1u << 20));
    f16* Vh  = (f16*)(base + 8  * (1u << 20));
    f16* cat = (f16*)(base + 12 * (1u << 20));
    f16* WoB = (f16*)(base + 16 * (1u << 20));
    float* y = (float*)(base + 18 * (1u << 20));
    (void)HSD;

    wo_convert<<<(E * E / 4) / 256, 256, 0, stream>>>(Wo, WoB);
    qkv_head<<<S, 256, 0, stream>>>(x, Wk, Wq, Wv, hWk, hbk, hWv, hbv, hWq, hbq,
                                    Kh, Qh, Vh);
    attn_mfma<<<dim3(S / TQ, H), 256, 0, stream>>>(Qh, Kh, Vh, cat);
    gemm_y<<<dim3(S / 64, E / 64), 256, 0, stream>>>(cat, WoB, bo, x, y);
    ln<<<S, 256, 0, stream>>>(y, gamma, beta, out);
}

// Round 7
// 291.047 us; speedup vs baseline: 17.8937x; 2.5975x over previous
//
#include <hip/hip_runtime.h>
#include <hip/hip_bf16.h>
#include <math.h>

#define S 2048
#define E 1024
#define D 64
#define H 16

using f16 = _Float16;
typedef _Float16 v8h __attribute__((ext_vector_type(8)));  // 8 fp16 (4 VGPRs)
typedef _Float16 v4h __attribute__((ext_vector_type(4)));
typedef float v4f __attribute__((ext_vector_type(4)));

// ---------------------------------------------------------------------------
// Kernel 0a: x fp32 -> fp16
// ---------------------------------------------------------------------------
__global__ void x_convert(const float* __restrict__ x, f16* __restrict__ Xh) {
    const size_t i = (size_t)blockIdx.x * 256 + threadIdx.x;
    v4f w = ((const v4f*)x)[i];
    v4h h = {(f16)w[0], (f16)w[1], (f16)w[2], (f16)w[3]};
    ((v4h*)Xh)[i] = h;
}

// ---------------------------------------------------------------------------
// Kernel 0b: Wo fp32 -> fp16
// ---------------------------------------------------------------------------
__global__ void wo_convert(const float* __restrict__ Wo, f16* __restrict__ WoB) {
    const size_t i = (size_t)blockIdx.x * 256 + threadIdx.x;
    v4f w = ((const v4f*)Wo)[i];
    v4h h = {(f16)w[0], (f16)w[1], (f16)w[2], (f16)w[3]};
    ((v4h*)WoB)[i] = h;
}

// ---------------------------------------------------------------------------
// Kernel 0c: folded weights  Wc[type,h] = hW[type,h] ([D,D]) @ W[type] ([D,E])
// stored as Wc[(th*D + e2)*E + e], fp16.  grid = (48, E/64), block = 256.
// ---------------------------------------------------------------------------
__global__ void wprep(const float* __restrict__ hWk, const float* __restrict__ hWq,
                      const float* __restrict__ hWv,
                      const float* __restrict__ Wk, const float* __restrict__ Wq,
                      const float* __restrict__ Wv,
                      f16* __restrict__ Wc) {
    const int th = blockIdx.x;          // 0..47
    const int type = th >> 4, h = th & 15;
    const int e0 = blockIdx.y * 64;
    const float* hW = ((type == 0) ? hWk : (type == 1) ? hWq : hWv) + (size_t)h * D * D;
    const float* W  = (type == 0) ? Wk : (type == 1) ? Wq : Wv;
    const int t = threadIdx.x;

    __shared__ f16 Ah[64][72];   // hW [e2][d]
    __shared__ f16 Bt[64][72];   // W  [e_local][d]  (transposed tile)

    {
        const int r16 = t >> 4, c4 = (t & 15) * 4;
#pragma unroll
        for (int rep = 0; rep < 4; ++rep) {
            const int row = rep * 16 + r16;
            v4f a = *(const v4f*)&hW[(size_t)row * D + c4];
#pragma unroll
            for (int j = 0; j < 4; ++j) Ah[row][c4 + j] = (f16)a[j];
            v4f w = *(const v4f*)&W[(size_t)row * E + e0 + c4];   // row = d
#pragma unroll
            for (int j = 0; j < 4; ++j) Bt[c4 + j][row] = (f16)w[j];
        }
    }
    __syncthreads();

    const int wave = t >> 6, lane = t & 63;
    const int quad = lane >> 4, l16 = lane & 15;
    v4f acc[4] = {{0,0,0,0},{0,0,0,0},{0,0,0,0},{0,0,0,0}};
#pragma unroll
    for (int ks = 0; ks < 2; ++ks) {
        v8h af = *(const v8h*)&Ah[wave * 16 + l16][ks * 32 + quad * 8];
#pragma unroll
        for (int nt = 0; nt < 4; ++nt) {
            v8h bf = *(const v8h*)&Bt[nt * 16 + l16][ks * 32 + quad * 8];
            acc[nt] = __builtin_amdgcn_mfma_f32_16x16x32_f16(af, bf, acc[nt], 0, 0, 0);
        }
    }
#pragma unroll
    for (int r = 0; r < 4; ++r) {
        const int e2 = wave * 16 + quad * 4 + r;
#pragma unroll
        for (int nt = 0; nt < 4; ++nt)
            Wc[((size_t)th * D + e2) * E + e0 + nt * 16 + l16] = (f16)acc[nt][r];
    }
}

// ---------------------------------------------------------------------------
// Kernel 1: QKV+head as one GEMM:  out = Xh ([S,E]) @ Wc^T ([3072,E]) + bias.
// Writes Kh/Qh/Vh [H,S,D] fp16 directly. tile 64x64, grid (S/64, 3072/64).
// ---------------------------------------------------------------------------
#define GPAD 40

__global__ void qkv_gemm(const f16* __restrict__ Xh,
                         const f16* __restrict__ Wc,
                         const float* __restrict__ hbk, const float* __restrict__ hbq,
                         const float* __restrict__ hbv,
                         f16* __restrict__ Kh, f16* __restrict__ Qh, f16* __restrict__ Vh) {
    const int m0 = blockIdx.x * 64;
    const int n0 = blockIdx.y * 64;
    const int type = n0 >> 10, h = (n0 >> 6) & 15;
    const float* hb = ((type == 0) ? hbk : (type == 1) ? hbq : hbv) + h * D;
    f16* outp = (type == 0) ? Kh : (type == 1) ? Qh : Vh;

    const int t = threadIdx.x;
    const int wave = t >> 6, lane = t & 63;
    const int quad = lane >> 4, l16 = lane & 15;

    __shared__ f16 At[64][GPAD];
    __shared__ f16 Bt[64][GPAD];

    v4f acc[4] = {{0,0,0,0},{0,0,0,0},{0,0,0,0},{0,0,0,0}};

    const int sr = t >> 2, sc = (t & 3) * 8;
    for (int k0 = 0; k0 < E; k0 += 32) {
        __syncthreads();
        *(v8h*)&At[sr][sc] = *(const v8h*)(Xh + (size_t)(m0 + sr) * E + k0 + sc);
        *(v8h*)&Bt[sr][sc] = *(const v8h*)(Wc + (size_t)(n0 + sr) * E + k0 + sc);
        __syncthreads();

        v8h af = *(const v8h*)&At[wave * 16 + l16][quad * 8];
#pragma unroll
        for (int nt = 0; nt < 4; ++nt) {
            v8h bf = *(const v8h*)&Bt[nt * 16 + l16][quad * 8];
            acc[nt] = __builtin_amdgcn_mfma_f32_16x16x32_f16(af, bf, acc[nt], 0, 0, 0);
        }
    }

#pragma unroll
    for (int r = 0; r < 4; ++r) {
        const int s = m0 + wave * 16 + quad * 4 + r;
#pragma unroll
        for (int nt = 0; nt < 4; ++nt) {
            const int d = nt * 16 + l16;
            outp[((size_t)h * S + s) * D + d] = (f16)(acc[nt][r] + hb[d]);
        }
    }
}

// ---------------------------------------------------------------------------
// Kernel 2: MFMA flash attention (fp16). One block = 1 head x 64 q-rows.
// grid = (S/64, H), block = 256.
// ---------------------------------------------------------------------------
#define TQ 64
#define TK 32
#define KPAD 72
#define VPAD 40
#define PPAD 40

__global__ void attn_mfma(const f16* __restrict__ Qh,
                          const f16* __restrict__ Kh,
                          const f16* __restrict__ Vh,
                          f16* __restrict__ cat) {
    const int h = blockIdx.y;
    const int q0 = blockIdx.x * TQ;
    const int t = threadIdx.x;
    const int wave = t >> 6, lane = t & 63;
    const int quad = lane >> 4, l16 = lane & 15;

    __shared__ f16 Kt[TK][KPAD];        // [key][d]
    __shared__ f16 Vt[D][VPAD];         // [d][key]
    __shared__ f16 Pt[4][16][PPAD];     // per-wave P [q-row][key]

    const int qrow = q0 + wave * 16 + l16;
    v8h qf[2];
    {
        const v8h* qp = (const v8h*)(Qh + ((size_t)h * S + qrow) * D);
        qf[0] = qp[quad];
        qf[1] = qp[quad + 4];
    }

    v4f oc[4] = {{0,0,0,0},{0,0,0,0},{0,0,0,0},{0,0,0,0}};
    float m_run[4], l_run[4];
#pragma unroll
    for (int r = 0; r < 4; ++r) { m_run[r] = -INFINITY; l_run[r] = 0.f; }

    const float scale = 0.125f * 1.44269504f;  // 1/sqrt(D) * log2(e)

    for (int k0 = 0; k0 < S; k0 += TK) {
        __syncthreads();
        {
            const int r = t >> 3, c = (t & 7) * 8;
            *(v8h*)&Kt[r][c] = *(const v8h*)(Kh + ((size_t)h * S + k0 + r) * D + c);
            v8h vv = *(const v8h*)(Vh + ((size_t)h * S + k0 + r) * D + c);
#pragma unroll
            for (int j = 0; j < 8; ++j) Vt[c + j][r] = vv[j];
        }
        __syncthreads();

        v4f sc0 = {0,0,0,0}, sc1 = {0,0,0,0};
#pragma unroll
        for (int ks = 0; ks < 2; ++ks) {
            v8h kf0 = *(const v8h*)&Kt[l16][quad * 8 + ks * 32];
            v8h kf1 = *(const v8h*)&Kt[l16 + 16][quad * 8 + ks * 32];
            sc0 = __builtin_amdgcn_mfma_f32_16x16x32_f16(qf[ks], kf0, sc0, 0, 0, 0);
            sc1 = __builtin_amdgcn_mfma_f32_16x16x32_f16(qf[ks], kf1, sc1, 0, 0, 0);
        }

#pragma unroll
        for (int r = 0; r < 4; ++r) {
            float a = sc0[r] * scale, b = sc1[r] * scale;
            float v = fmaxf(a, b);
            v = fmaxf(v, __shfl_xor(v, 1, 16));
            v = fmaxf(v, __shfl_xor(v, 2, 16));
            v = fmaxf(v, __shfl_xor(v, 4, 16));
            v = fmaxf(v, __shfl_xor(v, 8, 16));
            const float mnew = fmaxf(m_run[r], v);
            const float p0 = exp2f(a - mnew);
            const float p1 = exp2f(b - mnew);
            float sum = p0 + p1;
            sum += __shfl_xor(sum, 1, 16);
            sum += __shfl_xor(sum, 2, 16);
            sum += __shfl_xor(sum, 4, 16);
            sum += __shfl_xor(sum, 8, 16);
            const float alpha = exp2f(m_run[r] - mnew);
            l_run[r] = l_run[r] * alpha + sum;
            m_run[r] = mnew;
#pragma unroll
            for (int nt = 0; nt < 4; ++nt) oc[nt][r] *= alpha;
            Pt[wave][quad * 4 + r][l16]      = (f16)p0;
            Pt[wave][quad * 4 + r][l16 + 16] = (f16)p1;
        }
        __syncthreads();

        v8h pf = *(const v8h*)&Pt[wave][l16][quad * 8];
#pragma unroll
        for (int nt = 0; nt < 4; ++nt) {
            v8h vf = *(const v8h*)&Vt[nt * 16 + l16][quad * 8];
            oc[nt] = __builtin_amdgcn_mfma_f32_16x16x32_f16(pf, vf, oc[nt], 0, 0, 0);
        }
    }

#pragma unroll
    for (int r = 0; r < 4; ++r) {
        const float invl = 1.f / l_run[r];
        const int qg = q0 + wave * 16 + quad * 4 + r;
        f16* crow = cat + (size_t)qg * E + h * D;
#pragma unroll
        for (int nt = 0; nt < 4; ++nt)
            crow[nt * 16 + l16] = (f16)(oc[nt][r] * invl);
    }
}

// ---------------------------------------------------------------------------
// Kernel 3: MFMA GEMM  y[s,e] = cat[s,:]·WoB[e,:] + bo[e] + x[s,e]  (fp32 y)
// tile 64x64, grid (S/64, E/64), block 256.
// ---------------------------------------------------------------------------
__global__ void gemm_y(const f16* __restrict__ cat,
                       const f16* __restrict__ WoB,
                       const float* __restrict__ bo,
                       const float* __restrict__ x,
                       float* __restrict__ y) {
    const int m0 = blockIdx.x * 64;
    const int n0 = blockIdx.y * 64;
    const int t = threadIdx.x;
    const int wave = t >> 6, lane = t & 63;
    const int quad = lane >> 4, l16 = lane & 15;

    __shared__ f16 At[64][GPAD];
    __shared__ f16 Bt[64][GPAD];

    v4f acc[4] = {{0,0,0,0},{0,0,0,0},{0,0,0,0},{0,0,0,0}};

    const int sr = t >> 2, sc = (t & 3) * 8;
    for (int k0 = 0; k0 < E; k0 += 32) {
        __syncthreads();
        *(v8h*)&At[sr][sc] = *(const v8h*)(cat + (size_t)(m0 + sr) * E + k0 + sc);
        *(v8h*)&Bt[sr][sc] = *(const v8h*)(WoB + (size_t)(n0 + sr) * E + k0 + sc);
        __syncthreads();

        v8h af = *(const v8h*)&At[wave * 16 + l16][quad * 8];
#pragma unroll
        for (int nt = 0; nt < 4; ++nt) {
            v8h bf = *(const v8h*)&Bt[nt * 16 + l16][quad * 8];
            acc[nt] = __builtin_amdgcn_mfma_f32_16x16x32_f16(af, bf, acc[nt], 0, 0, 0);
        }
    }

#pragma unroll
    for (int r = 0; r < 4; ++r) {
        const int m = m0 + wave * 16 + quad * 4 + r;
#pragma unroll
        for (int nt = 0; nt < 4; ++nt) {
            const int e = n0 + nt * 16 + l16;
            y[(size_t)m * E + e] = acc[nt][r] + bo[e] + x[(size_t)m * E + e];
        }
    }
}

// ---------------------------------------------------------------------------
// Kernel 4: LayerNorm rows of y -> fp32 out. grid = S, block = 256.
// ---------------------------------------------------------------------------
__global__ void ln(const float* __restrict__ y,
                   const float* __restrict__ gamma,
                   const float* __restrict__ beta,
                   float* __restrict__ out) {
    const int s = blockIdx.x;
    const int t = threadIdx.x;
    __shared__ float red[256];

    float yv[4];
    float lsum = 0.f;
#pragma unroll
    for (int i = 0; i < 4; ++i) {
        yv[i] = y[(size_t)s * E + t + i * 256];
        lsum += yv[i];
    }
    red[t] = lsum;
    __syncthreads();
    for (int w = 128; w > 0; w >>= 1) {
        if (t < w) red[t] += red[t + w];
        __syncthreads();
    }
    const float mu = red[0] * (1.f / E);
    __syncthreads();

    float lv = 0.f;
#pragma unroll
    for (int i = 0; i < 4; ++i) { float dd = yv[i] - mu; lv += dd * dd; }
    red[t] = lv;
    __syncthreads();
    for (int w = 128; w > 0; w >>= 1) {
        if (t < w) red[t] += red[t + w];
        __syncthreads();
    }
    const float rstd = rsqrtf(red[0] * (1.f / E) + 1e-5f);

#pragma unroll
    for (int i = 0; i < 4; ++i) {
        const int e = t + i * 256;
        out[(size_t)s * E + e] = (yv[i] - mu) * rstd * gamma[e] + beta[e];
    }
}

// ---------------------------------------------------------------------------
extern "C" void kernel_launch(void* const* d_in, const int* in_sizes, int n_in,
                              void* d_out, int out_size, void* d_ws, size_t ws_size,
                              hipStream_t stream) {
    const float* x     = (const float*)d_in[0];
    const float* Wk    = (const float*)d_in[1];
    const float* Wq    = (const float*)d_in[2];
    const float* Wv    = (const float*)d_in[3];
    const float* hWk   = (const float*)d_in[4];
    const float* hbk   = (const float*)d_in[5];
    const float* hWv   = (const float*)d_in[6];
    const float* hbv   = (const float*)d_in[7];
    const float* hWq   = (const float*)d_in[8];
    const float* hbq   = (const float*)d_in[9];
    const float* Wo    = (const float*)d_in[10];
    const float* bo    = (const float*)d_in[11];
    const float* gamma = (const float*)d_in[12];
    const float* beta  = (const float*)d_in[13];
    float* out = (float*)d_out;

    // ws layout (MB):
    //   Xh  @  0 (4)  | Wc @ 4 (6) | WoB @ 10 (2) | Kh @ 12 (4) | Qh @ 16 (4)
    //   Vh  @ 20 (4)  | cat @ 24 (4)
    //   y   @  0 (8)  -- overlaps Xh+Wc, both dead once gemm_y runs
    // peak = 28 MB (ws >= 32 MB proven in round 4).
    char* base = (char*)d_ws;
    f16*  Xh  = (f16*)(base);
    f16*  Wc  = (f16*)(base + 4  * (1u << 20));
    f16*  WoB = (f16*)(base + 10 * (1u << 20));
    f16*  Kh  = (f16*)(base + 12 * (1u << 20));
    f16*  Qh  = (f16*)(base + 16 * (1u << 20));
    f16*  Vh  = (f16*)(base + 20 * (1u << 20));
    f16*  cat = (f16*)(base + 24 * (1u << 20));
    float* y  = (float*)(base);

    x_convert<<<(S * E / 4) / 256, 256, 0, stream>>>(x, Xh);
    wo_convert<<<(E * E / 4) / 256, 256, 0, stream>>>(Wo, WoB);
    wprep<<<dim3(3 * H, E / 64), 256, 0, stream>>>(hWk, hWq, hWv, Wk, Wq, Wv, Wc);
    qkv_gemm<<<dim3(S / 64, 3 * H * D / 64), 256, 0, stream>>>(Xh, Wc, hbk, hbq, hbv,
                                                               Kh, Qh, Vh);
    attn_mfma<<<dim3(S / TQ, H), 256, 0, stream>>>(Qh, Kh, Vh, cat);
    gemm_y<<<dim3(S / 64, E / 64), 256, 0, stream>>>(cat, WoB, bo, x, y);
    ln<<<S, 256, 0, stream>>>(y, gamma, beta, out);
}

// Round 8
// 222.227 us; speedup vs baseline: 23.4351x; 1.3097x over previous
//
#include <hip/hip_runtime.h>
#include <hip/hip_bf16.h>
#include <math.h>

#define S 2048
#define E 1024
#define D 64
#define H 16

using f16 = _Float16;
typedef _Float16 v8h __attribute__((ext_vector_type(8)));  // 8 fp16 (4 VGPRs)
typedef _Float16 v4h __attribute__((ext_vector_type(4)));
typedef float v4f __attribute__((ext_vector_type(4)));

// ---------------------------------------------------------------------------
// Kernel 0a: x fp32 -> fp16
// ---------------------------------------------------------------------------
__global__ void x_convert(const float* __restrict__ x, f16* __restrict__ Xh) {
    const size_t i = (size_t)blockIdx.x * 256 + threadIdx.x;
    v4f w = ((const v4f*)x)[i];
    v4h h = {(f16)w[0], (f16)w[1], (f16)w[2], (f16)w[3]};
    ((v4h*)Xh)[i] = h;
}

// ---------------------------------------------------------------------------
// Kernel 0b: Wo fp32 -> fp16
// ---------------------------------------------------------------------------
__global__ void wo_convert(const float* __restrict__ Wo, f16* __restrict__ WoB) {
    const size_t i = (size_t)blockIdx.x * 256 + threadIdx.x;
    v4f w = ((const v4f*)Wo)[i];
    v4h h = {(f16)w[0], (f16)w[1], (f16)w[2], (f16)w[3]};
    ((v4h*)WoB)[i] = h;
}

// ---------------------------------------------------------------------------
// Kernel 0c: folded weights  Wc[type,h] = hW[type,h] ([D,D]) @ W[type] ([D,E])
// stored as Wc[(th*D + e2)*E + e], fp16.  grid = (48, E/64), block = 256.
// ---------------------------------------------------------------------------
__global__ void wprep(const float* __restrict__ hWk, const float* __restrict__ hWq,
                      const float* __restrict__ hWv,
                      const float* __restrict__ Wk, const float* __restrict__ Wq,
                      const float* __restrict__ Wv,
                      f16* __restrict__ Wc) {
    const int th = blockIdx.x;          // 0..47
    const int type = th >> 4, h = th & 15;
    const int e0 = blockIdx.y * 64;
    const float* hW = ((type == 0) ? hWk : (type == 1) ? hWq : hWv) + (size_t)h * D * D;
    const float* W  = (type == 0) ? Wk : (type == 1) ? Wq : Wv;
    const int t = threadIdx.x;

    __shared__ f16 Ah[64][72];   // hW [e2][d]
    __shared__ f16 Bt[64][72];   // W  [e_local][d]  (transposed tile)

    {
        const int r16 = t >> 4, c4 = (t & 15) * 4;
#pragma unroll
        for (int rep = 0; rep < 4; ++rep) {
            const int row = rep * 16 + r16;
            v4f a = *(const v4f*)&hW[(size_t)row * D + c4];
#pragma unroll
            for (int j = 0; j < 4; ++j) Ah[row][c4 + j] = (f16)a[j];
            v4f w = *(const v4f*)&W[(size_t)row * E + e0 + c4];   // row = d
#pragma unroll
            for (int j = 0; j < 4; ++j) Bt[c4 + j][row] = (f16)w[j];
        }
    }
    __syncthreads();

    const int wave = t >> 6, lane = t & 63;
    const int quad = lane >> 4, l16 = lane & 15;
    v4f acc[4] = {{0,0,0,0},{0,0,0,0},{0,0,0,0},{0,0,0,0}};
#pragma unroll
    for (int ks = 0; ks < 2; ++ks) {
        v8h af = *(const v8h*)&Ah[wave * 16 + l16][ks * 32 + quad * 8];
#pragma unroll
        for (int nt = 0; nt < 4; ++nt) {
            v8h bf = *(const v8h*)&Bt[nt * 16 + l16][ks * 32 + quad * 8];
            acc[nt] = __builtin_amdgcn_mfma_f32_16x16x32_f16(af, bf, acc[nt], 0, 0, 0);
        }
    }
#pragma unroll
    for (int r = 0; r < 4; ++r) {
        const int e2 = wave * 16 + quad * 4 + r;
#pragma unroll
        for (int nt = 0; nt < 4; ++nt)
            Wc[((size_t)th * D + e2) * E + e0 + nt * 16 + l16] = (f16)acc[nt][r];
    }
}

// ---------------------------------------------------------------------------
// Kernel 1: QKV+head as one GEMM:  out = Xh ([S,E]) @ Wc^T ([3072,E]) + bias.
// Writes Kh/Qh/Vh [H,S,D] fp16 directly. tile 64x64, grid (S/64, 3072/64).
// ---------------------------------------------------------------------------
#define GPAD 40

__global__ void qkv_gemm(const f16* __restrict__ Xh,
                         const f16* __restrict__ Wc,
                         const float* __restrict__ hbk, const float* __restrict__ hbq,
                         const float* __restrict__ hbv,
                         f16* __restrict__ Kh, f16* __restrict__ Qh, f16* __restrict__ Vh) {
    const int m0 = blockIdx.x * 64;
    const int n0 = blockIdx.y * 64;
    const int type = n0 >> 10, h = (n0 >> 6) & 15;
    const float* hb = ((type == 0) ? hbk : (type == 1) ? hbq : hbv) + h * D;
    f16* outp = (type == 0) ? Kh : (type == 1) ? Qh : Vh;

    const int t = threadIdx.x;
    const int wave = t >> 6, lane = t & 63;
    const int quad = lane >> 4, l16 = lane & 15;

    __shared__ f16 At[64][GPAD];
    __shared__ f16 Bt[64][GPAD];

    v4f acc[4] = {{0,0,0,0},{0,0,0,0},{0,0,0,0},{0,0,0,0}};

    const int sr = t >> 2, sc = (t & 3) * 8;
    for (int k0 = 0; k0 < E; k0 += 32) {
        __syncthreads();
        *(v8h*)&At[sr][sc] = *(const v8h*)(Xh + (size_t)(m0 + sr) * E + k0 + sc);
        *(v8h*)&Bt[sr][sc] = *(const v8h*)(Wc + (size_t)(n0 + sr) * E + k0 + sc);
        __syncthreads();

        v8h af = *(const v8h*)&At[wave * 16 + l16][quad * 8];
#pragma unroll
        for (int nt = 0; nt < 4; ++nt) {
            v8h bf = *(const v8h*)&Bt[nt * 16 + l16][quad * 8];
            acc[nt] = __builtin_amdgcn_mfma_f32_16x16x32_f16(af, bf, acc[nt], 0, 0, 0);
        }
    }

#pragma unroll
    for (int r = 0; r < 4; ++r) {
        const int s = m0 + wave * 16 + quad * 4 + r;
#pragma unroll
        for (int nt = 0; nt < 4; ++nt) {
            const int d = nt * 16 + l16;
            outp[((size_t)h * S + s) * D + d] = (f16)(acc[nt][r] + hb[d]);
        }
    }
}

// ---------------------------------------------------------------------------
// Kernel 1b: Vh [h][s][d] -> VhT [h][d][s].  grid (H, S/64), block 256.
// LDS tile 64x64, stride 66 (2-way bank aliasing only = free).
// ---------------------------------------------------------------------------
__global__ void v_transpose(const f16* __restrict__ Vh, f16* __restrict__ VhT) {
    const int h = blockIdx.x;
    const int s0 = blockIdx.y * 64;
    const int t = threadIdx.x;

    __shared__ f16 T[64][66];

    {
        const int r = t >> 2, c = (t & 3) * 16;
        v8h a = *(const v8h*)(Vh + ((size_t)h * S + s0 + r) * D + c);
        v8h b = *(const v8h*)(Vh + ((size_t)h * S + s0 + r) * D + c + 8);
#pragma unroll
        for (int j = 0; j < 8; ++j) { T[r][c + j] = a[j]; T[r][c + 8 + j] = b[j]; }
    }
    __syncthreads();
    {
        const int d = t >> 2, sc = (t & 3) * 16;
        v8h a, b;
#pragma unroll
        for (int j = 0; j < 8; ++j) { a[j] = T[sc + j][d]; b[j] = T[sc + 8 + j][d]; }
        f16* o = VhT + ((size_t)h * D + d) * S + s0 + sc;
        *(v8h*)o = a;
        *(v8h*)(o + 8) = b;
    }
}

// ---------------------------------------------------------------------------
// Kernel 2: MFMA flash attention, K-split. One block = 1 head x 64 q-rows x
// 1024 keys (split sp). TK=64, register-prefetched staging, no V transpose
// in-loop (VhT pre-transposed), Pt is wave-private (no barrier after write).
// grid = (S/64, H, 2), block = 256.
// Writes normalized partial O (fp16) + per-row (m, l) in log2 domain.
// ---------------------------------------------------------------------------
#define TK2 64
#define NSPLIT 2
#define KSPAN (S / NSPLIT)      // 1024
#define ITERS (KSPAN / TK2)     // 16
#define APAD 72

__global__ void attn_mfma(const f16* __restrict__ Qh,
                          const f16* __restrict__ Kh,
                          const f16* __restrict__ VhT,
                          f16* __restrict__ Opart,
                          float* __restrict__ ml) {
    const int h = blockIdx.y;
    const int q0 = blockIdx.x * 64;
    const int sp = blockIdx.z;
    const int t = threadIdx.x;
    const int wave = t >> 6, lane = t & 63;
    const int quad = lane >> 4, l16 = lane & 15;

    __shared__ f16 Kt[TK2][APAD];        // [key][d]
    __shared__ f16 Vt[D][APAD];          // [d][key]
    __shared__ f16 Pt[4][16][APAD];      // per-wave P [q-row][key]

    // Q fragments (A-layout), K-dim = D = 64 -> 2 ks steps
    const int qrow = q0 + wave * 16 + l16;
    v8h qf[2];
    {
        const v8h* qp = (const v8h*)(Qh + ((size_t)h * S + qrow) * D);
        qf[0] = qp[quad];
        qf[1] = qp[quad + 4];
    }

    v4f oc[4] = {{0,0,0,0},{0,0,0,0},{0,0,0,0},{0,0,0,0}};
    float m_run[4], l_run[4];
#pragma unroll
    for (int r = 0; r < 4; ++r) { m_run[r] = -INFINITY; l_run[r] = 0.f; }

    const float scale = 0.125f * 1.44269504f;  // 1/sqrt(D) * log2(e)

    // staging mapping: thread t -> row r = t>>2 (64 rows), cols c..c+15
    const int sr = t >> 2, scc = (t & 3) * 16;
    const int kb = sp * KSPAN;

    v8h kA, kB, vA, vB;
    {
        const f16* kg = Kh + ((size_t)h * S + kb + sr) * D + scc;
        kA = *(const v8h*)kg; kB = *(const v8h*)(kg + 8);
        const f16* vg = VhT + ((size_t)h * D + sr) * S + kb + scc;
        vA = *(const v8h*)vg; vB = *(const v8h*)(vg + 8);
    }

    for (int it = 0; it < ITERS; ++it) {
        __syncthreads();                 // prior compute done reading Kt/Vt
        *(v8h*)&Kt[sr][scc] = kA;  *(v8h*)&Kt[sr][scc + 8] = kB;
        *(v8h*)&Vt[sr][scc] = vA;  *(v8h*)&Vt[sr][scc + 8] = vB;
        __syncthreads();                 // tiles visible

        if (it + 1 < ITERS) {            // prefetch next tile (retires under compute)
            const int nb = kb + (it + 1) * TK2;
            const f16* kg = Kh + ((size_t)h * S + nb + sr) * D + scc;
            kA = *(const v8h*)kg; kB = *(const v8h*)(kg + 8);
            const f16* vg = VhT + ((size_t)h * D + sr) * S + nb + scc;
            vA = *(const v8h*)vg; vB = *(const v8h*)(vg + 8);
        }

        // QK^T: 16 q-rows x 64 keys = 4 n-tiles, 2 ks steps
        v4f sc[4] = {{0,0,0,0},{0,0,0,0},{0,0,0,0},{0,0,0,0}};
#pragma unroll
        for (int ks = 0; ks < 2; ++ks) {
#pragma unroll
            for (int nt = 0; nt < 4; ++nt) {
                v8h kf = *(const v8h*)&Kt[nt * 16 + l16][ks * 32 + quad * 8];
                sc[nt] = __builtin_amdgcn_mfma_f32_16x16x32_f16(qf[ks], kf, sc[nt], 0, 0, 0);
            }
        }

        // online softmax; C-layout row = quad*4+r, cols l16 + 16*nt
#pragma unroll
        for (int r = 0; r < 4; ++r) {
            float a0 = sc[0][r] * scale, a1 = sc[1][r] * scale;
            float a2 = sc[2][r] * scale, a3 = sc[3][r] * scale;
            float v = fmaxf(fmaxf(a0, a1), fmaxf(a2, a3));
            v = fmaxf(v, __shfl_xor(v, 1, 16));
            v = fmaxf(v, __shfl_xor(v, 2, 16));
            v = fmaxf(v, __shfl_xor(v, 4, 16));
            v = fmaxf(v, __shfl_xor(v, 8, 16));
            const float mnew = fmaxf(m_run[r], v);
            const float p0 = exp2f(a0 - mnew), p1 = exp2f(a1 - mnew);
            const float p2 = exp2f(a2 - mnew), p3 = exp2f(a3 - mnew);
            float sum = (p0 + p1) + (p2 + p3);
            sum += __shfl_xor(sum, 1, 16);
            sum += __shfl_xor(sum, 2, 16);
            sum += __shfl_xor(sum, 4, 16);
            sum += __shfl_xor(sum, 8, 16);
            const float alpha = exp2f(m_run[r] - mnew);
            l_run[r] = l_run[r] * alpha + sum;
            m_run[r] = mnew;
#pragma unroll
            for (int nt = 0; nt < 4; ++nt) oc[nt][r] *= alpha;
            const int pr = quad * 4 + r;
            Pt[wave][pr][l16]      = (f16)p0;
            Pt[wave][pr][l16 + 16] = (f16)p1;
            Pt[wave][pr][l16 + 32] = (f16)p2;
            Pt[wave][pr][l16 + 48] = (f16)p3;
        }
        // Pt is wave-private: in-wave lgkmcnt ordering suffices, no barrier.

        // PV: O(16 x 64) += P(16 x 64) @ V^T-tiles, 4 n-tiles x 2 ks
        v8h pf0 = *(const v8h*)&Pt[wave][l16][quad * 8];
        v8h pf1 = *(const v8h*)&Pt[wave][l16][quad * 8 + 32];
#pragma unroll
        for (int nt = 0; nt < 4; ++nt) {
            v8h vf0 = *(const v8h*)&Vt[nt * 16 + l16][quad * 8];
            v8h vf1 = *(const v8h*)&Vt[nt * 16 + l16][quad * 8 + 32];
            oc[nt] = __builtin_amdgcn_mfma_f32_16x16x32_f16(pf0, vf0, oc[nt], 0, 0, 0);
            oc[nt] = __builtin_amdgcn_mfma_f32_16x16x32_f16(pf1, vf1, oc[nt], 0, 0, 0);
        }
    }

    // epilogue: normalized partial O + (m, l)
#pragma unroll
    for (int r = 0; r < 4; ++r) {
        const float invl = 1.f / l_run[r];
        const int qg = q0 + wave * 16 + quad * 4 + r;
        f16* orow = Opart + (((size_t)sp * H + h) * S + qg) * D;
#pragma unroll
        for (int nt = 0; nt < 4; ++nt)
            orow[nt * 16 + l16] = (f16)(oc[nt][r] * invl);
        if (l16 == 0) {
            float* mlp = ml + (((size_t)sp * H + h) * S + qg) * 2;
            mlp[0] = m_run[r];
            mlp[1] = l_run[r];
        }
    }
}

// ---------------------------------------------------------------------------
// Kernel 2b: combine the 2 splits -> cat[q][h*D+d] fp16. grid = S, block 256.
// ---------------------------------------------------------------------------
__global__ void attn_combine(const f16* __restrict__ Opart,
                             const float* __restrict__ ml,
                             f16* __restrict__ cat) {
    const int q = blockIdx.x;
    const int t = threadIdx.x;
#pragma unroll
    for (int i = 0; i < 4; ++i) {
        const int idx = i * 256 + t;          // h*64 + d
        const int h = idx >> 6, d = idx & 63;
        const size_t b0 = ((size_t)0 * H + h) * S + q;
        const size_t b1 = ((size_t)1 * H + h) * S + q;
        const float m0 = ml[b0 * 2], l0 = ml[b0 * 2 + 1];
        const float m1 = ml[b1 * 2], l1 = ml[b1 * 2 + 1];
        const float M = fmaxf(m0, m1);
        const float a0 = exp2f(m0 - M) * l0;
        const float a1 = exp2f(m1 - M) * l1;
        const float inv = 1.f / (a0 + a1);
        const float o = (a0 * (float)Opart[b0 * D + d] + a1 * (float)Opart[b1 * D + d]) * inv;
        cat[(size_t)q * E + h * D + d] = (f16)o;
    }
}

// ---------------------------------------------------------------------------
// Kernel 3: MFMA GEMM  y[s,e] = cat[s,:]·WoB[e,:] + bo[e] + x[s,e]  (fp32 y)
// tile 64x64, grid (S/64, E/64), block 256.
// ---------------------------------------------------------------------------
__global__ void gemm_y(const f16* __restrict__ cat,
                       const f16* __restrict__ WoB,
                       const float* __restrict__ bo,
                       const float* __restrict__ x,
                       float* __restrict__ y) {
    const int m0 = blockIdx.x * 64;
    const int n0 = blockIdx.y * 64;
    const int t = threadIdx.x;
    const int wave = t >> 6, lane = t & 63;
    const int quad = lane >> 4, l16 = lane & 15;

    __shared__ f16 At[64][GPAD];
    __shared__ f16 Bt[64][GPAD];

    v4f acc[4] = {{0,0,0,0},{0,0,0,0},{0,0,0,0},{0,0,0,0}};

    const int sr = t >> 2, sc = (t & 3) * 8;
    for (int k0 = 0; k0 < E; k0 += 32) {
        __syncthreads();
        *(v8h*)&At[sr][sc] = *(const v8h*)(cat + (size_t)(m0 + sr) * E + k0 + sc);
        *(v8h*)&Bt[sr][sc] = *(const v8h*)(WoB + (size_t)(n0 + sr) * E + k0 + sc);
        __syncthreads();

        v8h af = *(const v8h*)&At[wave * 16 + l16][quad * 8];
#pragma unroll
        for (int nt = 0; nt < 4; ++nt) {
            v8h bf = *(const v8h*)&Bt[nt * 16 + l16][quad * 8];
            acc[nt] = __builtin_amdgcn_mfma_f32_16x16x32_f16(af, bf, acc[nt], 0, 0, 0);
        }
    }

#pragma unroll
    for (int r = 0; r < 4; ++r) {
        const int m = m0 + wave * 16 + quad * 4 + r;
#pragma unroll
        for (int nt = 0; nt < 4; ++nt) {
            const int e = n0 + nt * 16 + l16;
            y[(size_t)m * E + e] = acc[nt][r] + bo[e] + x[(size_t)m * E + e];
        }
    }
}

// ---------------------------------------------------------------------------
// Kernel 4: LayerNorm rows of y -> fp32 out. grid = S, block = 256.
// ---------------------------------------------------------------------------
__global__ void ln(const float* __restrict__ y,
                   const float* __restrict__ gamma,
                   const float* __restrict__ beta,
                   float* __restrict__ out) {
    const int s = blockIdx.x;
    const int t = threadIdx.x;
    __shared__ float red[256];

    float yv[4];
    float lsum = 0.f;
#pragma unroll
    for (int i = 0; i < 4; ++i) {
        yv[i] = y[(size_t)s * E + t + i * 256];
        lsum += yv[i];
    }
    red[t] = lsum;
    __syncthreads();
    for (int w = 128; w > 0; w >>= 1) {
        if (t < w) red[t] += red[t + w];
        __syncthreads();
    }
    const float mu = red[0] * (1.f / E);
    __syncthreads();

    float lv = 0.f;
#pragma unroll
    for (int i = 0; i < 4; ++i) { float dd = yv[i] - mu; lv += dd * dd; }
    red[t] = lv;
    __syncthreads();
    for (int w = 128; w > 0; w >>= 1) {
        if (t < w) red[t] += red[t + w];
        __syncthreads();
    }
    const float rstd = rsqrtf(red[0] * (1.f / E) + 1e-5f);

#pragma unroll
    for (int i = 0; i < 4; ++i) {
        const int e = t + i * 256;
        out[(size_t)s * E + e] = (yv[i] - mu) * rstd * gamma[e] + beta[e];
    }
}

// ---------------------------------------------------------------------------
extern "C" void kernel_launch(void* const* d_in, const int* in_sizes, int n_in,
                              void* d_out, int out_size, void* d_ws, size_t ws_size,
                              hipStream_t stream) {
    const float* x     = (const float*)d_in[0];
    const float* Wk    = (const float*)d_in[1];
    const float* Wq    = (const float*)d_in[2];
    const float* Wv    = (const float*)d_in[3];
    const float* hWk   = (const float*)d_in[4];
    const float* hbk   = (const float*)d_in[5];
    const float* hWv   = (const float*)d_in[6];
    const float* hbv   = (const float*)d_in[7];
    const float* hWq   = (const float*)d_in[8];
    const float* hbq   = (const float*)d_in[9];
    const float* Wo    = (const float*)d_in[10];
    const float* bo    = (const float*)d_in[11];
    const float* gamma = (const float*)d_in[12];
    const float* beta  = (const float*)d_in[13];
    float* out = (float*)d_out;

    // ws layout (MB), peak 30.5 <= 32 (proven in round 4):
    //   Xh @0(4) [dead after qkv_gemm]        -> VhT @0(4) [attn]  -> y @0-8 [gemm_y]
    //   Wc @4(6) [dead after qkv_gemm]        -> Opart @4(8) [dead after combine]
    //   Kh @12(4) | Qh @16(4) | Vh @20(4) [dead after v_transpose]
    //   cat @24(4) | WoB @28(2) | ml @30(0.5)
    char* base = (char*)d_ws;
    const size_t MB = 1u << 20;
    f16*   Xh    = (f16*)(base);
    f16*   Wc    = (f16*)(base + 4 * MB);
    f16*   Kh    = (f16*)(base + 12 * MB);
    f16*   Qh    = (f16*)(base + 16 * MB);
    f16*   Vh    = (f16*)(base + 20 * MB);
    f16*   VhT   = (f16*)(base);
    f16*   Opart = (f16*)(base + 4 * MB);
    f16*   cat   = (f16*)(base + 24 * MB);
    f16*   WoB   = (f16*)(base + 28 * MB);
    float* ml    = (float*)(base + 30 * MB);
    float* y     = (float*)(base);

    x_convert<<<(S * E / 4) / 256, 256, 0, stream>>>(x, Xh);
    wo_convert<<<(E * E / 4) / 256, 256, 0, stream>>>(Wo, WoB);
    wprep<<<dim3(3 * H, E / 64), 256, 0, stream>>>(hWk, hWq, hWv, Wk, Wq, Wv, Wc);
    qkv_gemm<<<dim3(S / 64, 3 * H * D / 64), 256, 0, stream>>>(Xh, Wc, hbk, hbq, hbv,
                                                               Kh, Qh, Vh);
    v_transpose<<<dim3(H, S / 64), 256, 0, stream>>>(Vh, VhT);
    attn_mfma<<<dim3(S / 64, H, NSPLIT), 256, 0, stream>>>(Qh, Kh, VhT, Opart, ml);
    attn_combine<<<S, 256, 0, stream>>>(Opart, ml, cat);
    gemm_y<<<dim3(S / 64, E / 64), 256, 0, stream>>>(cat, WoB, bo, x, y);
    ln<<<S, 256, 0, stream>>>(y, gamma, beta, out);
}

// Round 9
// 179.536 us; speedup vs baseline: 29.0076x; 1.2378x over previous
//
#include <hip/hip_runtime.h>
#include <math.h>

#define S 2048
#define E 1024
#define D 64
#define H 16

using f16 = _Float16;
typedef _Float16 v8h __attribute__((ext_vector_type(8)));  // 8 fp16 (4 VGPRs)
typedef _Float16 v4h __attribute__((ext_vector_type(4)));
typedef float v4f __attribute__((ext_vector_type(4)));

// async global->LDS, 16 B per lane; LDS dest = wave-uniform base + lane*16
__device__ __forceinline__ void glds16(const f16* g, f16* l) {
    __builtin_amdgcn_global_load_lds(
        (const __attribute__((address_space(1))) void*)g,
        (__attribute__((address_space(3))) void*)l, 16, 0, 0);
}

// ---------------------------------------------------------------------------
// Kernel 0a/0b: fp32 -> fp16 converts
// ---------------------------------------------------------------------------
__global__ void x_convert(const float* __restrict__ x, f16* __restrict__ Xh) {
    const size_t i = (size_t)blockIdx.x * 256 + threadIdx.x;
    v4f w = ((const v4f*)x)[i];
    v4h h = {(f16)w[0], (f16)w[1], (f16)w[2], (f16)w[3]};
    ((v4h*)Xh)[i] = h;
}
__global__ void wo_convert(const float* __restrict__ Wo, f16* __restrict__ WoB) {
    const size_t i = (size_t)blockIdx.x * 256 + threadIdx.x;
    v4f w = ((const v4f*)Wo)[i];
    v4h h = {(f16)w[0], (f16)w[1], (f16)w[2], (f16)w[3]};
    ((v4h*)WoB)[i] = h;
}

// ---------------------------------------------------------------------------
// Kernel 0c: folded weights  Wc[type,h] = hW[type,h] @ W[type]   (unchanged)
// ---------------------------------------------------------------------------
__global__ void wprep(const float* __restrict__ hWk, const float* __restrict__ hWq,
                      const float* __restrict__ hWv,
                      const float* __restrict__ Wk, const float* __restrict__ Wq,
                      const float* __restrict__ Wv,
                      f16* __restrict__ Wc) {
    const int th = blockIdx.x;          // 0..47
    const int type = th >> 4, h = th & 15;
    const int e0 = blockIdx.y * 64;
    const float* hW = ((type == 0) ? hWk : (type == 1) ? hWq : hWv) + (size_t)h * D * D;
    const float* W  = (type == 0) ? Wk : (type == 1) ? Wq : Wv;
    const int t = threadIdx.x;

    __shared__ f16 Ah[64][72];
    __shared__ f16 Bt[64][72];

    {
        const int r16 = t >> 4, c4 = (t & 15) * 4;
#pragma unroll
        for (int rep = 0; rep < 4; ++rep) {
            const int row = rep * 16 + r16;
            v4f a = *(const v4f*)&hW[(size_t)row * D + c4];
#pragma unroll
            for (int j = 0; j < 4; ++j) Ah[row][c4 + j] = (f16)a[j];
            v4f w = *(const v4f*)&W[(size_t)row * E + e0 + c4];
#pragma unroll
            for (int j = 0; j < 4; ++j) Bt[c4 + j][row] = (f16)w[j];
        }
    }
    __syncthreads();

    const int wave = t >> 6, lane = t & 63;
    const int quad = lane >> 4, l16 = lane & 15;
    v4f acc[4] = {{0,0,0,0},{0,0,0,0},{0,0,0,0},{0,0,0,0}};
#pragma unroll
    for (int ks = 0; ks < 2; ++ks) {
        v8h af = *(const v8h*)&Ah[wave * 16 + l16][ks * 32 + quad * 8];
#pragma unroll
        for (int nt = 0; nt < 4; ++nt) {
            v8h bf = *(const v8h*)&Bt[nt * 16 + l16][ks * 32 + quad * 8];
            acc[nt] = __builtin_amdgcn_mfma_f32_16x16x32_f16(af, bf, acc[nt], 0, 0, 0);
        }
    }
#pragma unroll
    for (int r = 0; r < 4; ++r) {
        const int e2 = wave * 16 + quad * 4 + r;
#pragma unroll
        for (int nt = 0; nt < 4; ++nt)
            Wc[((size_t)th * D + e2) * E + e0 + nt * 16 + l16] = (f16)acc[nt][r];
    }
}

// ---------------------------------------------------------------------------
// Kernel 1: QKV GEMM, m97 recipe. tile 128x64, BK=64, global_load_lds w/ XOR
// granule swizzle (slot = g ^ (row&7)); rows are 64 f16 = 8 granules of 16 B.
// grid (S/128, 3072/64), block 256 (waves 2x2: wave=(wm,wn) -> 64x32).
// ---------------------------------------------------------------------------
__global__ __launch_bounds__(256) void qkv_gemm(
        const f16* __restrict__ Xh, const f16* __restrict__ Wc,
        const float* __restrict__ hbk, const float* __restrict__ hbq,
        const float* __restrict__ hbv,
        f16* __restrict__ Kh, f16* __restrict__ Qh, f16* __restrict__ Vh) {
    const int m0 = blockIdx.x * 128;
    const int n0 = blockIdx.y * 64;               // over 3072
    const int type = n0 >> 10, h = (n0 >> 6) & 15;
    const float* hb = ((type == 0) ? hbk : (type == 1) ? hbq : hbv) + h * D;
    f16* outp = (type == 0) ? Kh : (type == 1) ? Qh : Vh;

    const int t = threadIdx.x;
    const int wave = t >> 6, lane = t & 63;
    const int quad = lane >> 4, l16 = lane & 15;
    const int wm = wave >> 1, wn = wave & 1;

    __shared__ f16 As[128 * 64];
    __shared__ f16 Bs[64 * 64];

    v4f acc[4][2] = {};

    const int lrow8 = lane >> 3, lg = lane & 7;

    for (int k0 = 0; k0 < E; k0 += 64) {
        __syncthreads();
#pragma unroll
        for (int jj = 0; jj < 4; ++jj) {           // A: 16 instrs, 4 per wave
            const int j = wave * 4 + jj;
            const int row = j * 8 + lrow8;
            const int g = lg ^ (row & 7);
            glds16(Xh + (size_t)(m0 + row) * E + k0 + g * 8, &As[j * 512]);
        }
#pragma unroll
        for (int jj = 0; jj < 2; ++jj) {           // B: 8 instrs, 2 per wave
            const int j = wave * 2 + jj;
            const int row = j * 8 + lrow8;
            const int g = lg ^ (row & 7);
            glds16(Wc + (size_t)(n0 + row) * E + k0 + g * 8, &Bs[j * 512]);
        }
        __syncthreads();

#pragma unroll
        for (int ks = 0; ks < 2; ++ks) {
            v8h a[4], b[2];
#pragma unroll
            for (int mt = 0; mt < 4; ++mt) {
                const int row = wm * 64 + mt * 16 + l16;
                a[mt] = *(const v8h*)&As[row * 64 + (((ks * 4 + quad) ^ (row & 7)) * 8)];
            }
#pragma unroll
            for (int nt = 0; nt < 2; ++nt) {
                const int row = wn * 32 + nt * 16 + l16;
                b[nt] = *(const v8h*)&Bs[row * 64 + (((ks * 4 + quad) ^ (row & 7)) * 8)];
            }
#pragma unroll
            for (int mt = 0; mt < 4; ++mt)
#pragma unroll
                for (int nt = 0; nt < 2; ++nt)
                    acc[mt][nt] = __builtin_amdgcn_mfma_f32_16x16x32_f16(a[mt], b[nt], acc[mt][nt], 0, 0, 0);
        }
    }

#pragma unroll
    for (int mt = 0; mt < 4; ++mt)
#pragma unroll
        for (int r = 0; r < 4; ++r) {
            const int s = m0 + wm * 64 + mt * 16 + quad * 4 + r;
#pragma unroll
            for (int nt = 0; nt < 2; ++nt) {
                const int d = wn * 32 + nt * 16 + l16;
                outp[((size_t)h * S + s) * D + d] = (f16)(acc[mt][nt][r] + hb[d]);
            }
        }
}

// ---------------------------------------------------------------------------
// Kernel 1b: Vh [h][s][d] -> VhT [h][d][s].  (unchanged)
// ---------------------------------------------------------------------------
__global__ void v_transpose(const f16* __restrict__ Vh, f16* __restrict__ VhT) {
    const int h = blockIdx.x;
    const int s0 = blockIdx.y * 64;
    const int t = threadIdx.x;

    __shared__ f16 T[64][66];

    {
        const int r = t >> 2, c = (t & 3) * 16;
        v8h a = *(const v8h*)(Vh + ((size_t)h * S + s0 + r) * D + c);
        v8h b = *(const v8h*)(Vh + ((size_t)h * S + s0 + r) * D + c + 8);
#pragma unroll
        for (int j = 0; j < 8; ++j) { T[r][c + j] = a[j]; T[r][c + 8 + j] = b[j]; }
    }
    __syncthreads();
    {
        const int d = t >> 2, sc = (t & 3) * 16;
        v8h a, b;
#pragma unroll
        for (int j = 0; j < 8; ++j) { a[j] = T[sc + j][d]; b[j] = T[sc + 8 + j][d]; }
        f16* o = VhT + ((size_t)h * D + d) * S + s0 + sc;
        *(v8h*)o = a;
        *(v8h*)(o + 8) = b;
    }
}

// ---------------------------------------------------------------------------
// Kernel 2: MFMA flash attention, TRANSPOSED scores (K@Q^T -> C[key][q]).
// Per lane all 16 score values belong to one q (= lane&15): reductions are
// 15 register ops + 2 shuffles. PV computed as O^T = V^T @ P^T; O^T is
// transposed back through LDS in the epilogue. grid (S/64, H, 2), block 256.
// ---------------------------------------------------------------------------
#define TK2 64
#define NSPLIT 2
#define KSPAN (S / NSPLIT)      // 1024
#define ITERS (KSPAN / TK2)     // 16
#define APAD 72

__global__ __launch_bounds__(256) void attn_mfma(
        const f16* __restrict__ Qh, const f16* __restrict__ Kh,
        const f16* __restrict__ VhT, f16* __restrict__ Opart,
        float* __restrict__ ml) {
    const int h = blockIdx.y;
    const int q0 = blockIdx.x * 64;
    const int sp = blockIdx.z;
    const int t = threadIdx.x;
    const int wave = t >> 6, lane = t & 63;
    const int quad = lane >> 4, l16 = lane & 15;

    __shared__ f16 Kt[TK2][APAD];        // [key][d]
    __shared__ f16 Vt[D][APAD];          // [d][key]
    __shared__ f16 Pt[4][16][APAD];      // per-wave P^T as [q][key]
    __shared__ f16 Ot[64][APAD];         // O^T transpose-back buffer [q][d]

    // Q fragment: B-operand [n=q][k=d], lane l16 = q
    const int qrow = q0 + wave * 16 + l16;
    v8h qf[2];
    {
        const v8h* qp = (const v8h*)(Qh + ((size_t)h * S + qrow) * D);
        qf[0] = qp[quad];
        qf[1] = qp[quad + 4];
    }

    v4f oc[4] = {};                      // O^T C-frags: [d-tile][reg], col=q
    float m_run = -INFINITY, l_run = 0.f;
    const float scale = 0.125f * 1.44269504f;   // 1/sqrt(D) * log2(e)

    const int sr = t >> 2, scc = (t & 3) * 16;
    const int kb = sp * KSPAN;

    v8h kA, kB, vA, vB;
    {
        const f16* kg = Kh + ((size_t)h * S + kb + sr) * D + scc;
        kA = *(const v8h*)kg; kB = *(const v8h*)(kg + 8);
        const f16* vg = VhT + ((size_t)h * D + sr) * S + kb + scc;
        vA = *(const v8h*)vg; vB = *(const v8h*)(vg + 8);
    }

    for (int it = 0; it < ITERS; ++it) {
        __syncthreads();
        *(v8h*)&Kt[sr][scc] = kA;  *(v8h*)&Kt[sr][scc + 8] = kB;
        *(v8h*)&Vt[sr][scc] = vA;  *(v8h*)&Vt[sr][scc + 8] = vB;
        __syncthreads();

        if (it + 1 < ITERS) {
            const int nb = kb + (it + 1) * TK2;
            const f16* kg = Kh + ((size_t)h * S + nb + sr) * D + scc;
            kA = *(const v8h*)kg; kB = *(const v8h*)(kg + 8);
            const f16* vg = VhT + ((size_t)h * D + sr) * S + nb + scc;
            vA = *(const v8h*)vg; vB = *(const v8h*)(vg + 8);
        }

        // scores^T: C[key][q], 4 key m-tiles, A = K-tile, B = Q-frag
        v4f sc[4] = {};
#pragma unroll
        for (int ks = 0; ks < 2; ++ks) {
#pragma unroll
            for (int mt = 0; mt < 4; ++mt) {
                v8h kf = *(const v8h*)&Kt[mt * 16 + l16][ks * 32 + quad * 8];
                sc[mt] = __builtin_amdgcn_mfma_f32_16x16x32_f16(kf, qf[ks], sc[mt], 0, 0, 0);
            }
        }

        // softmax for q = l16: 16 in-register values + 2 cross-quad shuffles
        float v = sc[0][0];
#pragma unroll
        for (int mt = 0; mt < 4; ++mt)
#pragma unroll
            for (int r = 0; r < 4; ++r) v = fmaxf(v, sc[mt][r]);
        v = fmaxf(v, __shfl_xor(v, 16));
        v = fmaxf(v, __shfl_xor(v, 32));
        v *= scale;
        const float mnew = fmaxf(m_run, v);
        const float alpha = exp2f(m_run - mnew);   // first iter: exp2(-inf)=0
        m_run = mnew;

        float tsum = 0.f;
#pragma unroll
        for (int mt = 0; mt < 4; ++mt) {
            v4h ph;
#pragma unroll
            for (int r = 0; r < 4; ++r) {
                const float p = exp2f(fmaf(sc[mt][r], scale, -mnew));
                tsum += p;
                ph[r] = (f16)p;
            }
            *(v4h*)&Pt[wave][l16][mt * 16 + quad * 4] = ph;   // P^T [q][key]
        }
        tsum += __shfl_xor(tsum, 16);
        tsum += __shfl_xor(tsum, 32);
        l_run = l_run * alpha + tsum;
#pragma unroll
        for (int mt = 0; mt < 4; ++mt) oc[mt] *= alpha;
        // Pt is wave-private; per-wave DS ordering makes writes visible.

        // PV: O^T = V^T @ P^T. A = Vt [d][key], B = Pt [q][key].
#pragma unroll
        for (int ks = 0; ks < 2; ++ks) {
            v8h pf = *(const v8h*)&Pt[wave][l16][ks * 32 + quad * 8];
#pragma unroll
            for (int mt = 0; mt < 4; ++mt) {
                v8h vf = *(const v8h*)&Vt[mt * 16 + l16][ks * 32 + quad * 8];
                oc[mt] = __builtin_amdgcn_mfma_f32_16x16x32_f16(vf, pf, oc[mt], 0, 0, 0);
            }
        }
    }

    // epilogue: normalize, transpose O^T -> O through LDS, coalesced store
    const float invl = 1.f / l_run;
#pragma unroll
    for (int mt = 0; mt < 4; ++mt) {
        v4h oh;
#pragma unroll
        for (int r = 0; r < 4; ++r) oh[r] = (f16)(oc[mt][r] * invl);
        *(v4h*)&Ot[wave * 16 + l16][mt * 16 + quad * 4] = oh;
    }
    if (quad == 0) {
        float* mlp = ml + (((size_t)sp * H + h) * S + qrow) * 2;
        mlp[0] = m_run;
        mlp[1] = l_run;
    }
    __syncthreads();
    {
        const int q = t >> 2, dg = (t & 3) * 16;
        v8h o0 = *(const v8h*)&Ot[q][dg];
        v8h o1 = *(const v8h*)&Ot[q][dg + 8];
        f16* dst = Opart + (((size_t)sp * H + h) * S + q0 + q) * D + dg;
        *(v8h*)dst = o0;
        *(v8h*)(dst + 8) = o1;
    }
}

// ---------------------------------------------------------------------------
// Kernel 2b: combine the 2 splits -> cat[q][h*D+d] fp16.  (unchanged)
// ---------------------------------------------------------------------------
__global__ void attn_combine(const f16* __restrict__ Opart,
                             const float* __restrict__ ml,
                             f16* __restrict__ cat) {
    const int q = blockIdx.x;
    const int t = threadIdx.x;
#pragma unroll
    for (int i = 0; i < 4; ++i) {
        const int idx = i * 256 + t;          // h*64 + d
        const int h = idx >> 6, d = idx & 63;
        const size_t b0 = ((size_t)0 * H + h) * S + q;
        const size_t b1 = ((size_t)1 * H + h) * S + q;
        const float m0 = ml[b0 * 2], l0 = ml[b0 * 2 + 1];
        const float m1 = ml[b1 * 2], l1 = ml[b1 * 2 + 1];
        const float M = fmaxf(m0, m1);
        const float a0 = exp2f(m0 - M) * l0;
        const float a1 = exp2f(m1 - M) * l1;
        const float inv = 1.f / (a0 + a1);
        const float o = (a0 * (float)Opart[b0 * D + d] + a1 * (float)Opart[b1 * D + d]) * inv;
        cat[(size_t)q * E + h * D + d] = (f16)o;
    }
}

// ---------------------------------------------------------------------------
// Kernel 3: out-proj GEMM, m97 recipe. tile 64x64, BK=64, glds + XOR swizzle.
// y[s,e] = cat[s,:]·WoB[e,:] + bo[e] + x[s,e]  (fp32 y). grid (S/64, E/64).
// ---------------------------------------------------------------------------
__global__ __launch_bounds__(256) void gemm_y(
        const f16* __restrict__ cat, const f16* __restrict__ WoB,
        const float* __restrict__ bo, const float* __restrict__ x,
        float* __restrict__ y) {
    const int m0 = blockIdx.x * 64;
    const int n0 = blockIdx.y * 64;
    const int t = threadIdx.x;
    const int wave = t >> 6, lane = t & 63;
    const int quad = lane >> 4, l16 = lane & 15;
    const int wm = wave >> 1, wn = wave & 1;

    __shared__ f16 As[64 * 64];
    __shared__ f16 Bs[64 * 64];

    v4f acc[2][2] = {};
    const int lrow8 = lane >> 3, lg = lane & 7;

    for (int k0 = 0; k0 < E; k0 += 64) {
        __syncthreads();
#pragma unroll
        for (int jj = 0; jj < 2; ++jj) {
            const int j = wave * 2 + jj;
            const int row = j * 8 + lrow8;
            const int g = lg ^ (row & 7);
            glds16(cat + (size_t)(m0 + row) * E + k0 + g * 8, &As[j * 512]);
            glds16(WoB + (size_t)(n0 + row) * E + k0 + g * 8, &Bs[j * 512]);
        }
        __syncthreads();

#pragma unroll
        for (int ks = 0; ks < 2; ++ks) {
            v8h a[2], b[2];
#pragma unroll
            for (int mt = 0; mt < 2; ++mt) {
                const int row = wm * 32 + mt * 16 + l16;
                a[mt] = *(const v8h*)&As[row * 64 + (((ks * 4 + quad) ^ (row & 7)) * 8)];
            }
#pragma unroll
            for (int nt = 0; nt < 2; ++nt) {
                const int row = wn * 32 + nt * 16 + l16;
                b[nt] = *(const v8h*)&Bs[row * 64 + (((ks * 4 + quad) ^ (row & 7)) * 8)];
            }
#pragma unroll
            for (int mt = 0; mt < 2; ++mt)
#pragma unroll
                for (int nt = 0; nt < 2; ++nt)
                    acc[mt][nt] = __builtin_amdgcn_mfma_f32_16x16x32_f16(a[mt], b[nt], acc[mt][nt], 0, 0, 0);
        }
    }

#pragma unroll
    for (int mt = 0; mt < 2; ++mt)
#pragma unroll
        for (int r = 0; r < 4; ++r) {
            const int m = m0 + wm * 32 + mt * 16 + quad * 4 + r;
#pragma unroll
            for (int nt = 0; nt < 2; ++nt) {
                const int e = n0 + wn * 32 + nt * 16 + l16;
                y[(size_t)m * E + e] = acc[mt][nt][r] + bo[e] + x[(size_t)m * E + e];
            }
        }
}

// ---------------------------------------------------------------------------
// Kernel 4: LayerNorm rows of y -> fp32 out. grid = S, block = 256.
// ---------------------------------------------------------------------------
__global__ void ln(const float* __restrict__ y,
                   const float* __restrict__ gamma,
                   const float* __restrict__ beta,
                   float* __restrict__ out) {
    const int s = blockIdx.x;
    const int t = threadIdx.x;
    __shared__ float red[256];

    v4f yv = *(const v4f*)(y + (size_t)s * E + t * 4);
    float lsum = yv[0] + yv[1] + yv[2] + yv[3];
    red[t] = lsum;
    __syncthreads();
    for (int w = 128; w > 0; w >>= 1) {
        if (t < w) red[t] += red[t + w];
        __syncthreads();
    }
    const float mu = red[0] * (1.f / E);
    __syncthreads();

    float lv = 0.f;
#pragma unroll
    for (int i = 0; i < 4; ++i) { float dd = yv[i] - mu; lv += dd * dd; }
    red[t] = lv;
    __syncthreads();
    for (int w = 128; w > 0; w >>= 1) {
        if (t < w) red[t] += red[t + w];
        __syncthreads();
    }
    const float rstd = rsqrtf(red[0] * (1.f / E) + 1e-5f);

    v4f o;
#pragma unroll
    for (int i = 0; i < 4; ++i) {
        const int e = t * 4 + i;
        o[i] = (yv[i] - mu) * rstd * gamma[e] + beta[e];
    }
    *(v4f*)(out + (size_t)s * E + t * 4) = o;
}

// ---------------------------------------------------------------------------
extern "C" void kernel_launch(void* const* d_in, const int* in_sizes, int n_in,
                              void* d_out, int out_size, void* d_ws, size_t ws_size,
                              hipStream_t stream) {
    const float* x     = (const float*)d_in[0];
    const float* Wk    = (const float*)d_in[1];
    const float* Wq    = (const float*)d_in[2];
    const float* Wv    = (const float*)d_in[3];
    const float* hWk   = (const float*)d_in[4];
    const float* hbk   = (const float*)d_in[5];
    const float* hWv   = (const float*)d_in[6];
    const float* hbv   = (const float*)d_in[7];
    const float* hWq   = (const float*)d_in[8];
    const float* hbq   = (const float*)d_in[9];
    const float* Wo    = (const float*)d_in[10];
    const float* bo    = (const float*)d_in[11];
    const float* gamma = (const float*)d_in[12];
    const float* beta  = (const float*)d_in[13];
    float* out = (float*)d_out;

    // ws layout (MB), peak 30.5 <= 32 (proven in round 4):
    //   Xh @0(4) [dead after qkv_gemm]  -> VhT @0(4) [attn] -> y @0-8 [gemm_y]
    //   Wc @4(6) [dead after qkv_gemm]  -> Opart @4(8) [dead after combine]
    //   Kh @12(4) | Qh @16(4) | Vh @20(4) [dead after v_transpose]
    //   cat @24(4) | WoB @28(2) | ml @30(0.5)
    char* base = (char*)d_ws;
    const size_t MB = 1u << 20;
    f16*   Xh    = (f16*)(base);
    f16*   Wc    = (f16*)(base + 4 * MB);
    f16*   Kh    = (f16*)(base + 12 * MB);
    f16*   Qh    = (f16*)(base + 16 * MB);
    f16*   Vh    = (f16*)(base + 20 * MB);
    f16*   VhT   = (f16*)(base);
    f16*   Opart = (f16*)(base + 4 * MB);
    f16*   cat   = (f16*)(base + 24 * MB);
    f16*   WoB   = (f16*)(base + 28 * MB);
    float* ml    = (float*)(base + 30 * MB);
    float* y     = (float*)(base);

    x_convert<<<(S * E / 4) / 256, 256, 0, stream>>>(x, Xh);
    wo_convert<<<(E * E / 4) / 256, 256, 0, stream>>>(Wo, WoB);
    wprep<<<dim3(3 * H, E / 64), 256, 0, stream>>>(hWk, hWq, hWv, Wk, Wq, Wv, Wc);
    qkv_gemm<<<dim3(S / 128, 3 * H * D / 64), 256, 0, stream>>>(Xh, Wc, hbk, hbq, hbv,
                                                                Kh, Qh, Vh);
    v_transpose<<<dim3(H, S / 64), 256, 0, stream>>>(Vh, VhT);
    attn_mfma<<<dim3(S / 64, H, NSPLIT), 256, 0, stream>>>(Qh, Kh, VhT, Opart, ml);
    attn_combine<<<S, 256, 0, stream>>>(Opart, ml, cat);
    gemm_y<<<dim3(S / 64, E / 64), 256, 0, stream>>>(cat, WoB, bo, x, y);
    ln<<<S, 256, 0, stream>>>(y, gamma, beta, out);
}

// Round 10
// 170.376 us; speedup vs baseline: 30.5671x; 1.0538x over previous
//
#include <hip/hip_runtime.h>
#include <math.h>

#define S 2048
#define E 1024
#define D 64
#define H 16

using f16 = _Float16;
typedef _Float16 v8h __attribute__((ext_vector_type(8)));  // 8 fp16 (4 VGPRs)
typedef _Float16 v4h __attribute__((ext_vector_type(4)));
typedef _Float16 v2h __attribute__((ext_vector_type(2)));
typedef float v4f __attribute__((ext_vector_type(4)));

__device__ __forceinline__ float fexp2(float x) { return __builtin_amdgcn_exp2f(x); }

// async global->LDS, 16 B per lane; LDS dest = wave-uniform base + lane*16
__device__ __forceinline__ void glds16(const f16* g, f16* l) {
    __builtin_amdgcn_global_load_lds(
        (const __attribute__((address_space(1))) void*)g,
        (__attribute__((address_space(3))) void*)l, 16, 0, 0);
}

// ---------------------------------------------------------------------------
// Kernel 0: fused fp32 -> fp16 converts (x then Wo). grid = 3072.
// ---------------------------------------------------------------------------
__global__ void convert_all(const float* __restrict__ x, const float* __restrict__ Wo,
                            f16* __restrict__ Xh, f16* __restrict__ WoB) {
    const size_t i = (size_t)blockIdx.x * 256 + threadIdx.x;
    const size_t NX = (size_t)S * E / 4;
    if (i < NX) {
        v4f w = ((const v4f*)x)[i];
        v4h h = {(f16)w[0], (f16)w[1], (f16)w[2], (f16)w[3]};
        ((v4h*)Xh)[i] = h;
    } else {
        const size_t j = i - NX;
        v4f w = ((const v4f*)Wo)[j];
        v4h h = {(f16)w[0], (f16)w[1], (f16)w[2], (f16)w[3]};
        ((v4h*)WoB)[j] = h;
    }
}

// ---------------------------------------------------------------------------
// Kernel 0c: folded weights  Wc[type,h] = hW[type,h] @ W[type]   (unchanged)
// ---------------------------------------------------------------------------
__global__ void wprep(const float* __restrict__ hWk, const float* __restrict__ hWq,
                      const float* __restrict__ hWv,
                      const float* __restrict__ Wk, const float* __restrict__ Wq,
                      const float* __restrict__ Wv,
                      f16* __restrict__ Wc) {
    const int th = blockIdx.x;          // 0..47
    const int type = th >> 4, h = th & 15;
    const int e0 = blockIdx.y * 64;
    const float* hW = ((type == 0) ? hWk : (type == 1) ? hWq : hWv) + (size_t)h * D * D;
    const float* W  = (type == 0) ? Wk : (type == 1) ? Wq : Wv;
    const int t = threadIdx.x;

    __shared__ f16 Ah[64][72];
    __shared__ f16 Bt[64][72];

    {
        const int r16 = t >> 4, c4 = (t & 15) * 4;
#pragma unroll
        for (int rep = 0; rep < 4; ++rep) {
            const int row = rep * 16 + r16;
            v4f a = *(const v4f*)&hW[(size_t)row * D + c4];
#pragma unroll
            for (int j = 0; j < 4; ++j) Ah[row][c4 + j] = (f16)a[j];
            v4f w = *(const v4f*)&W[(size_t)row * E + e0 + c4];
#pragma unroll
            for (int j = 0; j < 4; ++j) Bt[c4 + j][row] = (f16)w[j];
        }
    }
    __syncthreads();

    const int wave = t >> 6, lane = t & 63;
    const int quad = lane >> 4, l16 = lane & 15;
    v4f acc[4] = {{0,0,0,0},{0,0,0,0},{0,0,0,0},{0,0,0,0}};
#pragma unroll
    for (int ks = 0; ks < 2; ++ks) {
        v8h af = *(const v8h*)&Ah[wave * 16 + l16][ks * 32 + quad * 8];
#pragma unroll
        for (int nt = 0; nt < 4; ++nt) {
            v8h bf = *(const v8h*)&Bt[nt * 16 + l16][ks * 32 + quad * 8];
            acc[nt] = __builtin_amdgcn_mfma_f32_16x16x32_f16(af, bf, acc[nt], 0, 0, 0);
        }
    }
#pragma unroll
    for (int r = 0; r < 4; ++r) {
        const int e2 = wave * 16 + quad * 4 + r;
#pragma unroll
        for (int nt = 0; nt < 4; ++nt)
            Wc[((size_t)th * D + e2) * E + e0 + nt * 16 + l16] = (f16)acc[nt][r];
    }
}

// ---------------------------------------------------------------------------
// Kernel 1: QKV GEMM (m97 recipe, unchanged). grid (S/128, 3072/64), block 256.
// ---------------------------------------------------------------------------
__global__ __launch_bounds__(256) void qkv_gemm(
        const f16* __restrict__ Xh, const f16* __restrict__ Wc,
        const float* __restrict__ hbk, const float* __restrict__ hbq,
        const float* __restrict__ hbv,
        f16* __restrict__ Kh, f16* __restrict__ Qh, f16* __restrict__ Vh) {
    const int m0 = blockIdx.x * 128;
    const int n0 = blockIdx.y * 64;
    const int type = n0 >> 10, h = (n0 >> 6) & 15;
    const float* hb = ((type == 0) ? hbk : (type == 1) ? hbq : hbv) + h * D;
    f16* outp = (type == 0) ? Kh : (type == 1) ? Qh : Vh;

    const int t = threadIdx.x;
    const int wave = t >> 6, lane = t & 63;
    const int quad = lane >> 4, l16 = lane & 15;
    const int wm = wave >> 1, wn = wave & 1;

    __shared__ f16 As[128 * 64];
    __shared__ f16 Bs[64 * 64];

    v4f acc[4][2] = {};
    const int lrow8 = lane >> 3, lg = lane & 7;

    for (int k0 = 0; k0 < E; k0 += 64) {
        __syncthreads();
#pragma unroll
        for (int jj = 0; jj < 4; ++jj) {
            const int j = wave * 4 + jj;
            const int row = j * 8 + lrow8;
            const int g = lg ^ (row & 7);
            glds16(Xh + (size_t)(m0 + row) * E + k0 + g * 8, &As[j * 512]);
        }
#pragma unroll
        for (int jj = 0; jj < 2; ++jj) {
            const int j = wave * 2 + jj;
            const int row = j * 8 + lrow8;
            const int g = lg ^ (row & 7);
            glds16(Wc + (size_t)(n0 + row) * E + k0 + g * 8, &Bs[j * 512]);
        }
        __syncthreads();

#pragma unroll
        for (int ks = 0; ks < 2; ++ks) {
            v8h a[4], b[2];
#pragma unroll
            for (int mt = 0; mt < 4; ++mt) {
                const int row = wm * 64 + mt * 16 + l16;
                a[mt] = *(const v8h*)&As[row * 64 + (((ks * 4 + quad) ^ (row & 7)) * 8)];
            }
#pragma unroll
            for (int nt = 0; nt < 2; ++nt) {
                const int row = wn * 32 + nt * 16 + l16;
                b[nt] = *(const v8h*)&Bs[row * 64 + (((ks * 4 + quad) ^ (row & 7)) * 8)];
            }
#pragma unroll
            for (int mt = 0; mt < 4; ++mt)
#pragma unroll
                for (int nt = 0; nt < 2; ++nt)
                    acc[mt][nt] = __builtin_amdgcn_mfma_f32_16x16x32_f16(a[mt], b[nt], acc[mt][nt], 0, 0, 0);
        }
    }

#pragma unroll
    for (int mt = 0; mt < 4; ++mt)
#pragma unroll
        for (int r = 0; r < 4; ++r) {
            const int s = m0 + wm * 64 + mt * 16 + quad * 4 + r;
#pragma unroll
            for (int nt = 0; nt < 2; ++nt) {
                const int d = wn * 32 + nt * 16 + l16;
                outp[((size_t)h * S + s) * D + d] = (f16)(acc[mt][nt][r] + hb[d]);
            }
        }
}

// ---------------------------------------------------------------------------
// Kernel 1b: Vh [h][s][d] -> VhT [h][d][s].  (unchanged)
// ---------------------------------------------------------------------------
__global__ void v_transpose(const f16* __restrict__ Vh, f16* __restrict__ VhT) {
    const int h = blockIdx.x;
    const int s0 = blockIdx.y * 64;
    const int t = threadIdx.x;

    __shared__ f16 T[64][66];

    {
        const int r = t >> 2, c = (t & 3) * 16;
        v8h a = *(const v8h*)(Vh + ((size_t)h * S + s0 + r) * D + c);
        v8h b = *(const v8h*)(Vh + ((size_t)h * S + s0 + r) * D + c + 8);
#pragma unroll
        for (int j = 0; j < 8; ++j) { T[r][c + j] = a[j]; T[r][c + 8 + j] = b[j]; }
    }
    __syncthreads();
    {
        const int d = t >> 2, sc = (t & 3) * 16;
        v8h a, b;
#pragma unroll
        for (int j = 0; j < 8; ++j) { a[j] = T[sc + j][d]; b[j] = T[sc + 8 + j][d]; }
        f16* o = VhT + ((size_t)h * D + d) * S + s0 + sc;
        *(v8h*)o = a;
        *(v8h*)(o + 8) = b;
    }
}

// ---------------------------------------------------------------------------
// Kernel 2: MFMA flash attention v3.
//  - transposed scores K@Q^T (C[key][q], per-lane row softmax)
//  - glds16 staging into unpadded XOR-swizzled K/V tiles
//  - ones-tile in Vt rows [64,80) computes l via the PV MFMA (alpha-rescaled)
//  - Pt/Ot LDS union (barrier-protected) -> 27.6 KB, 5 blocks/CU
// grid = (S/64, H, 4), block = 256.
// ---------------------------------------------------------------------------
#define NSPLIT 4
#define KSPAN (S / NSPLIT)      // 512
#define ITERS (KSPAN / 64)      // 8
#define PPAD 72

__global__ __launch_bounds__(256, 5) void attn_mfma(
        const f16* __restrict__ Qh, const f16* __restrict__ Kh,
        const f16* __restrict__ VhT, f16* __restrict__ Opart,
        float* __restrict__ ml) {
    const int h = blockIdx.y;
    const int q0 = blockIdx.x * 64;
    const int sp = blockIdx.z;
    const int t = threadIdx.x;
    const int wave = t >> 6, lane = t & 63;
    const int quad = lane >> 4, l16 = lane & 15;

    __shared__ f16 Kt[64 * 64];          // [key][d], swizzled granules
    __shared__ f16 Vt[80 * 64];          // [d][key] rows 0-63; rows 64-79 = 1.0
    __shared__ union { f16 P[4][16][PPAD]; f16 O[64][PPAD]; } PO;

    // ones rows (written once; staging DMA never touches rows >= 64)
    {
        v4h one = {(f16)1, (f16)1, (f16)1, (f16)1};
        *(v4h*)&Vt[64 * 64 + t * 4] = one;
    }

    // Q fragment (B-operand: n = q = l16, k = d)
    const int qrow = q0 + wave * 16 + l16;
    v8h qf[2];
    {
        const v8h* qp = (const v8h*)(Qh + ((size_t)h * S + qrow) * D);
        qf[0] = qp[quad];
        qf[1] = qp[quad + 4];
    }

    v4f oc[5] = {};                      // [0..3]=O^T d-tiles, [4]=l (ones tile)
    float m_run = -INFINITY;
    const float scale = 0.125f * 1.44269504f;   // 1/sqrt(D) * log2(e)
    const int kb = sp * KSPAN;
    const int srow = lane >> 3, sg = lane & 7;  // staging: 8 rows x 8 granules

    for (int it = 0; it < ITERS; ++it) {
        __syncthreads();                 // prev compute done reading Kt/Vt
#pragma unroll
        for (int half = 0; half < 2; ++half) {
            const int row = wave * 16 + half * 8 + srow;
            const int g = sg ^ (row & 7);
            glds16(Kh + ((size_t)h * S + kb + it * 64 + row) * D + g * 8,
                   &Kt[(wave * 16 + half * 8) * 64]);
            glds16(VhT + ((size_t)h * D + row) * S + kb + it * 64 + g * 8,
                   &Vt[(wave * 16 + half * 8) * 64]);
        }
        __syncthreads();                 // DMA drained (vmcnt in barrier)

        // scores^T: C[key][q], A = K rows, B = Q frag
        v4f sc[4] = {};
#pragma unroll
        for (int ks = 0; ks < 2; ++ks)
#pragma unroll
            for (int mt = 0; mt < 4; ++mt) {
                const int key = mt * 16 + l16;
                v8h kf = *(const v8h*)&Kt[key * 64 + (((ks * 4 + quad) ^ (key & 7)) * 8)];
                sc[mt] = __builtin_amdgcn_mfma_f32_16x16x32_f16(kf, qf[ks], sc[mt], 0, 0, 0);
            }

        // softmax for q = l16 (16 in-register scores + 2 cross-quad shuffles)
        float v = sc[0][0];
#pragma unroll
        for (int mt = 0; mt < 4; ++mt)
#pragma unroll
            for (int r = 0; r < 4; ++r) v = fmaxf(v, sc[mt][r]);
        v = fmaxf(v, __shfl_xor(v, 16));
        v = fmaxf(v, __shfl_xor(v, 32));
        v *= scale;
        const float mnew = fmaxf(m_run, v);
        const float alpha = fexp2(m_run - mnew);   // first iter: exp2(-inf)=0
        m_run = mnew;
#pragma unroll
        for (int i = 0; i < 5; ++i) oc[i] *= alpha;

#pragma unroll
        for (int mt = 0; mt < 4; ++mt) {
            const float p0 = fexp2(fmaf(sc[mt][0], scale, -mnew));
            const float p1 = fexp2(fmaf(sc[mt][1], scale, -mnew));
            const float p2 = fexp2(fmaf(sc[mt][2], scale, -mnew));
            const float p3 = fexp2(fmaf(sc[mt][3], scale, -mnew));
            auto lo = __builtin_amdgcn_cvt_pkrtz(p0, p1);
            auto hi = __builtin_amdgcn_cvt_pkrtz(p2, p3);
            v4h ph; ph[0] = lo[0]; ph[1] = lo[1]; ph[2] = hi[0]; ph[3] = hi[1];
            *(v4h*)&PO.P[wave][l16][mt * 16 + quad * 4] = ph;   // P^T [q][key]
        }
        // Pt is wave-private; in-wave DS ordering suffices (no barrier).

        // PV: O^T = V^T @ P^T (+ ones tile -> l). A = Vt rows, B = P^T frag.
#pragma unroll
        for (int ks = 0; ks < 2; ++ks) {
            v8h pf = *(const v8h*)&PO.P[wave][l16][ks * 32 + quad * 8];
#pragma unroll
            for (int mt = 0; mt < 5; ++mt) {
                const int dr = mt * 16 + l16;
                v8h vf = *(const v8h*)&Vt[dr * 64 + (((ks * 4 + quad) ^ (dr & 7)) * 8)];
                oc[mt] = __builtin_amdgcn_mfma_f32_16x16x32_f16(vf, pf, oc[mt], 0, 0, 0);
            }
        }
    }

    // epilogue: l from ones tile; normalize; transpose O^T->O via LDS (union!)
    const float l = oc[4][0];            // all regs of ones tile equal l[q]
    const float invl = 1.f / l;
    __syncthreads();                     // all waves done with PO.P
#pragma unroll
    for (int mt = 0; mt < 4; ++mt) {
        auto lo = __builtin_amdgcn_cvt_pkrtz(oc[mt][0] * invl, oc[mt][1] * invl);
        auto hi = __builtin_amdgcn_cvt_pkrtz(oc[mt][2] * invl, oc[mt][3] * invl);
        v4h oh; oh[0] = lo[0]; oh[1] = lo[1]; oh[2] = hi[0]; oh[3] = hi[1];
        *(v4h*)&PO.O[wave * 16 + l16][mt * 16 + quad * 4] = oh;
    }
    if (quad == 0) {
        float* mlp = ml + (((size_t)sp * H + h) * S + qrow) * 2;
        mlp[0] = m_run;
        mlp[1] = l;
    }
    __syncthreads();
    {
        const int q = t >> 2, dg = (t & 3) * 16;
        v8h o0 = *(const v8h*)&PO.O[q][dg];
        v8h o1 = *(const v8h*)&PO.O[q][dg + 8];
        f16* dst = Opart + (((size_t)sp * H + h) * S + q0 + q) * D + dg;
        *(v8h*)dst = o0;
        *(v8h*)(dst + 8) = o1;
    }
}

// ---------------------------------------------------------------------------
// Kernel 2b: combine 4 splits -> cat[q][h*D+d] fp16. grid = S, block 256.
// ---------------------------------------------------------------------------
__global__ void attn_combine(const f16* __restrict__ Opart,
                             const float* __restrict__ ml,
                             f16* __restrict__ cat) {
    const int q = blockIdx.x;
    const int t = threadIdx.x;
#pragma unroll
    for (int i = 0; i < 4; ++i) {
        const int idx = i * 256 + t;          // h*64 + d
        const int h = idx >> 6, d = idx & 63;
        float m[NSPLIT], lv[NSPLIT];
        float M = -INFINITY;
#pragma unroll
        for (int sp = 0; sp < NSPLIT; ++sp) {
            const float* mlp = ml + (((size_t)sp * H + h) * S + q) * 2;
            m[sp] = mlp[0]; lv[sp] = mlp[1];
            M = fmaxf(M, m[sp]);
        }
        float asum = 0.f, o = 0.f;
#pragma unroll
        for (int sp = 0; sp < NSPLIT; ++sp) {
            const float a = fexp2(m[sp] - M) * lv[sp];
            asum += a;
            o += a * (float)Opart[(((size_t)sp * H + h) * S + q) * D + d];
        }
        cat[(size_t)q * E + h * D + d] = (f16)(o / asum);
    }
}

// ---------------------------------------------------------------------------
// Kernel 3: out-proj GEMM (m97 recipe, unchanged). grid (S/64, E/64).
// ---------------------------------------------------------------------------
__global__ __launch_bounds__(256) void gemm_y(
        const f16* __restrict__ cat, const f16* __restrict__ WoB,
        const float* __restrict__ bo, const float* __restrict__ x,
        float* __restrict__ y) {
    const int m0 = blockIdx.x * 64;
    const int n0 = blockIdx.y * 64;
    const int t = threadIdx.x;
    const int wave = t >> 6, lane = t & 63;
    const int quad = lane >> 4, l16 = lane & 15;
    const int wm = wave >> 1, wn = wave & 1;

    __shared__ f16 As[64 * 64];
    __shared__ f16 Bs[64 * 64];

    v4f acc[2][2] = {};
    const int lrow8 = lane >> 3, lg = lane & 7;

    for (int k0 = 0; k0 < E; k0 += 64) {
        __syncthreads();
#pragma unroll
        for (int jj = 0; jj < 2; ++jj) {
            const int j = wave * 2 + jj;
            const int row = j * 8 + lrow8;
            const int g = lg ^ (row & 7);
            glds16(cat + (size_t)(m0 + row) * E + k0 + g * 8, &As[j * 512]);
            glds16(WoB + (size_t)(n0 + row) * E + k0 + g * 8, &Bs[j * 512]);
        }
        __syncthreads();

#pragma unroll
        for (int ks = 0; ks < 2; ++ks) {
            v8h a[2], b[2];
#pragma unroll
            for (int mt = 0; mt < 2; ++mt) {
                const int row = wm * 32 + mt * 16 + l16;
                a[mt] = *(const v8h*)&As[row * 64 + (((ks * 4 + quad) ^ (row & 7)) * 8)];
            }
#pragma unroll
            for (int nt = 0; nt < 2; ++nt) {
                const int row = wn * 32 + nt * 16 + l16;
                b[nt] = *(const v8h*)&Bs[row * 64 + (((ks * 4 + quad) ^ (row & 7)) * 8)];
            }
#pragma unroll
            for (int mt = 0; mt < 2; ++mt)
#pragma unroll
                for (int nt = 0; nt < 2; ++nt)
                    acc[mt][nt] = __builtin_amdgcn_mfma_f32_16x16x32_f16(a[mt], b[nt], acc[mt][nt], 0, 0, 0);
        }
    }

#pragma unroll
    for (int mt = 0; mt < 2; ++mt)
#pragma unroll
        for (int r = 0; r < 4; ++r) {
            const int m = m0 + wm * 32 + mt * 16 + quad * 4 + r;
#pragma unroll
            for (int nt = 0; nt < 2; ++nt) {
                const int e = n0 + wn * 32 + nt * 16 + l16;
                y[(size_t)m * E + e] = acc[mt][nt][r] + bo[e] + x[(size_t)m * E + e];
            }
        }
}

// ---------------------------------------------------------------------------
// Kernel 4: LayerNorm rows of y -> fp32 out. grid = S, block = 256.
// ---------------------------------------------------------------------------
__global__ void ln(const float* __restrict__ y,
                   const float* __restrict__ gamma,
                   const float* __restrict__ beta,
                   float* __restrict__ out) {
    const int s = blockIdx.x;
    const int t = threadIdx.x;
    __shared__ float red[256];

    v4f yv = *(const v4f*)(y + (size_t)s * E + t * 4);
    red[t] = yv[0] + yv[1] + yv[2] + yv[3];
    __syncthreads();
    for (int w = 128; w > 0; w >>= 1) {
        if (t < w) red[t] += red[t + w];
        __syncthreads();
    }
    const float mu = red[0] * (1.f / E);
    __syncthreads();

    float lv = 0.f;
#pragma unroll
    for (int i = 0; i < 4; ++i) { float dd = yv[i] - mu; lv += dd * dd; }
    red[t] = lv;
    __syncthreads();
    for (int w = 128; w > 0; w >>= 1) {
        if (t < w) red[t] += red[t + w];
        __syncthreads();
    }
    const float rstd = rsqrtf(red[0] * (1.f / E) + 1e-5f);

    v4f o;
#pragma unroll
    for (int i = 0; i < 4; ++i) {
        const int e = t * 4 + i;
        o[i] = (yv[i] - mu) * rstd * gamma[e] + beta[e];
    }
    *(v4f*)(out + (size_t)s * E + t * 4) = o;
}

// ---------------------------------------------------------------------------
extern "C" void kernel_launch(void* const* d_in, const int* in_sizes, int n_in,
                              void* d_out, int out_size, void* d_ws, size_t ws_size,
                              hipStream_t stream) {
    const float* x     = (const float*)d_in[0];
    const float* Wk    = (const float*)d_in[1];
    const float* Wq    = (const float*)d_in[2];
    const float* Wv    = (const float*)d_in[3];
    const float* hWk   = (const float*)d_in[4];
    const float* hbk   = (const float*)d_in[5];
    const float* hWv   = (const float*)d_in[6];
    const float* hbv   = (const float*)d_in[7];
    const float* hWq   = (const float*)d_in[8];
    const float* hbq   = (const float*)d_in[9];
    const float* Wo    = (const float*)d_in[10];
    const float* bo    = (const float*)d_in[11];
    const float* gamma = (const float*)d_in[12];
    const float* beta  = (const float*)d_in[13];
    float* out = (float*)d_out;

    // ws layout (MB), peak 31 <= 32 (proven):
    //   Kh @0(4) | Qh @4(4) | VhT @8(4) | Opart @12(16) | ml @28(1) | WoB @29(2)
    //   Xh @12(4), Wc @16(6), Vh @22(4)  -- all dead before Opart is written
    //   cat @0(4)  -- after attn (Kh dead);  y @4(8) -- after attn (Qh/VhT dead)
    char* base = (char*)d_ws;
    const size_t MB = 1u << 20;
    f16*   Kh    = (f16*)(base);
    f16*   Qh    = (f16*)(base + 4 * MB);
    f16*   VhT   = (f16*)(base + 8 * MB);
    f16*   Opart = (f16*)(base + 12 * MB);
    float* ml    = (float*)(base + 28 * MB);
    f16*   WoB   = (f16*)(base + 29 * MB);
    f16*   Xh    = (f16*)(base + 12 * MB);
    f16*   Wc    = (f16*)(base + 16 * MB);
    f16*   Vh    = (f16*)(base + 22 * MB);
    f16*   cat   = (f16*)(base);
    float* y     = (float*)(base + 4 * MB);

    convert_all<<<3072, 256, 0, stream>>>(x, Wo, Xh, WoB);
    wprep<<<dim3(3 * H, E / 64), 256, 0, stream>>>(hWk, hWq, hWv, Wk, Wq, Wv, Wc);
    qkv_gemm<<<dim3(S / 128, 3 * H * D / 64), 256, 0, stream>>>(Xh, Wc, hbk, hbq, hbv,
                                                                Kh, Qh, Vh);
    v_transpose<<<dim3(H, S / 64), 256, 0, stream>>>(Vh, VhT);
    attn_mfma<<<dim3(S / 64, H, NSPLIT), 256, 0, stream>>>(Qh, Kh, VhT, Opart, ml);
    attn_combine<<<S, 256, 0, stream>>>(Opart, ml, cat);
    gemm_y<<<dim3(S / 64, E / 64), 256, 0, stream>>>(cat, WoB, bo, x, y);
    ln<<<S, 256, 0, stream>>>(y, gamma, beta, out);
}

// Round 12
// 166.947 us; speedup vs baseline: 31.1950x; 1.0205x over previous
//
#include <hip/hip_runtime.h>
#include <math.h>

#define S 2048
#define E 1024
#define D 64
#define H 16

using f16 = _Float16;
typedef _Float16 v8h __attribute__((ext_vector_type(8)));  // 8 fp16 (4 VGPRs)
typedef _Float16 v4h __attribute__((ext_vector_type(4)));
typedef float v4f __attribute__((ext_vector_type(4)));

__device__ __forceinline__ float fexp2(float x) { return __builtin_amdgcn_exp2f(x); }

// async global->LDS, 16 B per lane; LDS dest = wave-uniform base + lane*16
__device__ __forceinline__ void glds16(const f16* g, f16* l) {
    __builtin_amdgcn_global_load_lds(
        (const __attribute__((address_space(1))) void*)g,
        (__attribute__((address_space(3))) void*)l, 16, 0, 0);
}

// ---------------------------------------------------------------------------
// Kernel 0: fused prep. blocks [0,3072): x/Wo fp32->fp16 converts.
// blocks [3072, 3840): folded weights Wc[type,h] = hW[type,h] @ W[type].
// ---------------------------------------------------------------------------
__global__ void prep(const float* __restrict__ x, const float* __restrict__ Wo,
                     const float* __restrict__ hWk, const float* __restrict__ hWq,
                     const float* __restrict__ hWv,
                     const float* __restrict__ Wk, const float* __restrict__ Wq,
                     const float* __restrict__ Wv,
                     f16* __restrict__ Xh, f16* __restrict__ WoB,
                     f16* __restrict__ Wc) {
    __shared__ f16 Ah[64][72];
    __shared__ f16 Bt[64][72];
    const int t = threadIdx.x;

    if (blockIdx.x < 3072) {             // converts
        const size_t i = (size_t)blockIdx.x * 256 + t;
        const size_t NX = (size_t)S * E / 4;
        if (i < NX) {
            v4f w = ((const v4f*)x)[i];
            v4h h = {(f16)w[0], (f16)w[1], (f16)w[2], (f16)w[3]};
            ((v4h*)Xh)[i] = h;
        } else {
            const size_t j = i - NX;
            v4f w = ((const v4f*)Wo)[j];
            v4h h = {(f16)w[0], (f16)w[1], (f16)w[2], (f16)w[3]};
            ((v4h*)WoB)[j] = h;
        }
        return;
    }

    const int bb = blockIdx.x - 3072;    // 0..767
    const int th = bb >> 4;              // 0..47
    const int type = th >> 4, h = th & 15;
    const int e0 = (bb & 15) * 64;
    const float* hW = ((type == 0) ? hWk : (type == 1) ? hWq : hWv) + (size_t)h * D * D;
    const float* W  = (type == 0) ? Wk : (type == 1) ? Wq : Wv;

    {
        const int r16 = t >> 4, c4 = (t & 15) * 4;
#pragma unroll
        for (int rep = 0; rep < 4; ++rep) {
            const int row = rep * 16 + r16;
            v4f a = *(const v4f*)&hW[(size_t)row * D + c4];
#pragma unroll
            for (int j = 0; j < 4; ++j) Ah[row][c4 + j] = (f16)a[j];
            v4f w = *(const v4f*)&W[(size_t)row * E + e0 + c4];
#pragma unroll
            for (int j = 0; j < 4; ++j) Bt[c4 + j][row] = (f16)w[j];
        }
    }
    __syncthreads();

    const int wave = t >> 6, lane = t & 63;
    const int quad = lane >> 4, l16 = lane & 15;
    v4f acc[4] = {};
#pragma unroll
    for (int ks = 0; ks < 2; ++ks) {
        v8h af = *(const v8h*)&Ah[wave * 16 + l16][ks * 32 + quad * 8];
#pragma unroll
        for (int nt = 0; nt < 4; ++nt) {
            v8h bf = *(const v8h*)&Bt[nt * 16 + l16][ks * 32 + quad * 8];
            acc[nt] = __builtin_amdgcn_mfma_f32_16x16x32_f16(af, bf, acc[nt], 0, 0, 0);
        }
    }
#pragma unroll
    for (int r = 0; r < 4; ++r) {
        const int e2 = wave * 16 + quad * 4 + r;
#pragma unroll
        for (int nt = 0; nt < 4; ++nt)
            Wc[((size_t)th * D + e2) * E + e0 + nt * 16 + l16] = (f16)acc[nt][r];
    }
}

// ---------------------------------------------------------------------------
// Kernel 1: QKV GEMM (m97 recipe). K/Q written [h][s][d]; V written DIRECTLY
// TRANSPOSED to VhT [h][d][s]. grid (S/128, 3072/64), block 256.
// ---------------------------------------------------------------------------
__global__ __launch_bounds__(256) void qkv_gemm(
        const f16* __restrict__ Xh, const f16* __restrict__ Wc,
        const float* __restrict__ hbk, const float* __restrict__ hbq,
        const float* __restrict__ hbv,
        f16* __restrict__ Kh, f16* __restrict__ Qh, f16* __restrict__ VhT) {
    const int m0 = blockIdx.x * 128;
    const int n0 = blockIdx.y * 64;
    const int type = n0 >> 10, h = (n0 >> 6) & 15;
    const float* hb = ((type == 0) ? hbk : (type == 1) ? hbq : hbv) + h * D;

    const int t = threadIdx.x;
    const int wave = t >> 6, lane = t & 63;
    const int quad = lane >> 4, l16 = lane & 15;
    const int wm = wave >> 1, wn = wave & 1;

    __shared__ f16 As[128 * 64];
    __shared__ f16 Bs[64 * 64];

    v4f acc[4][2] = {};
    const int lrow8 = lane >> 3, lg = lane & 7;

    for (int k0 = 0; k0 < E; k0 += 64) {
        __syncthreads();
#pragma unroll
        for (int jj = 0; jj < 4; ++jj) {
            const int j = wave * 4 + jj;
            const int row = j * 8 + lrow8;
            const int g = lg ^ (row & 7);
            glds16(Xh + (size_t)(m0 + row) * E + k0 + g * 8, &As[j * 512]);
        }
#pragma unroll
        for (int jj = 0; jj < 2; ++jj) {
            const int j = wave * 2 + jj;
            const int row = j * 8 + lrow8;
            const int g = lg ^ (row & 7);
            glds16(Wc + (size_t)(n0 + row) * E + k0 + g * 8, &Bs[j * 512]);
        }
        __syncthreads();

#pragma unroll
        for (int ks = 0; ks < 2; ++ks) {
            v8h a[4], b[2];
#pragma unroll
            for (int mt = 0; mt < 4; ++mt) {
                const int row = wm * 64 + mt * 16 + l16;
                a[mt] = *(const v8h*)&As[row * 64 + (((ks * 4 + quad) ^ (row & 7)) * 8)];
            }
#pragma unroll
            for (int nt = 0; nt < 2; ++nt) {
                const int row = wn * 32 + nt * 16 + l16;
                b[nt] = *(const v8h*)&Bs[row * 64 + (((ks * 4 + quad) ^ (row & 7)) * 8)];
            }
#pragma unroll
            for (int mt = 0; mt < 4; ++mt)
#pragma unroll
                for (int nt = 0; nt < 2; ++nt)
                    acc[mt][nt] = __builtin_amdgcn_mfma_f32_16x16x32_f16(a[mt], b[nt], acc[mt][nt], 0, 0, 0);
        }
    }

    if (type == 2) {                     // V: write transposed [h][d][s]
#pragma unroll
        for (int mt = 0; mt < 4; ++mt)
#pragma unroll
            for (int nt = 0; nt < 2; ++nt) {
                const int d = wn * 32 + nt * 16 + l16;
                const int s = m0 + wm * 64 + mt * 16 + quad * 4;
                const float b = hb[d];
                v4h vh;
#pragma unroll
                for (int r = 0; r < 4; ++r) vh[r] = (f16)(acc[mt][nt][r] + b);
                *(v4h*)(VhT + ((size_t)h * D + d) * S + s) = vh;
            }
    } else {
        f16* outp = (type == 0) ? Kh : Qh;
#pragma unroll
        for (int mt = 0; mt < 4; ++mt)
#pragma unroll
            for (int r = 0; r < 4; ++r) {
                const int s = m0 + wm * 64 + mt * 16 + quad * 4 + r;
#pragma unroll
                for (int nt = 0; nt < 2; ++nt) {
                    const int d = wn * 32 + nt * 16 + l16;
                    outp[((size_t)h * S + s) * D + d] = (f16)(acc[mt][nt][r] + hb[d]);
                }
            }
    }
}

// ---------------------------------------------------------------------------
// Kernel 2: MFMA flash attention (round-10 proven version — ONLINE softmax).
//  - transposed scores K@Q^T (C[key][q], per-lane row softmax)
//  - glds16 staging into unpadded XOR-swizzled K/V tiles
//  - ones-tile in Vt rows [64,80) computes l via the PV MFMA (alpha-rescaled)
//  - Pt/Ot LDS union (barrier-protected)
// grid = (S/64, H, 4), block = 256.
// NOTE (r11 post-mortem): per-row max is load-bearing — raw-score*scale has
// sigma ~13 in log2 domain, row-max ~43; no fixed shift fits fp16.
// ---------------------------------------------------------------------------
#define NSPLIT 4
#define KSPAN (S / NSPLIT)      // 512
#define ITERS (KSPAN / 64)      // 8
#define PPAD 72

__global__ __launch_bounds__(256, 5) void attn_mfma(
        const f16* __restrict__ Qh, const f16* __restrict__ Kh,
        const f16* __restrict__ VhT, f16* __restrict__ Opart,
        float* __restrict__ ml) {
    const int h = blockIdx.y;
    const int q0 = blockIdx.x * 64;
    const int sp = blockIdx.z;
    const int t = threadIdx.x;
    const int wave = t >> 6, lane = t & 63;
    const int quad = lane >> 4, l16 = lane & 15;

    __shared__ f16 Kt[64 * 64];          // [key][d], swizzled granules
    __shared__ f16 Vt[80 * 64];          // [d][key] rows 0-63; rows 64-79 = 1.0
    __shared__ union { f16 P[4][16][PPAD]; f16 O[64][PPAD]; } PO;

    {
        v4h one = {(f16)1, (f16)1, (f16)1, (f16)1};
        *(v4h*)&Vt[64 * 64 + t * 4] = one;
    }

    const int qrow = q0 + wave * 16 + l16;
    v8h qf[2];
    {
        const v8h* qp = (const v8h*)(Qh + ((size_t)h * S + qrow) * D);
        qf[0] = qp[quad];
        qf[1] = qp[quad + 4];
    }

    v4f oc[5] = {};                      // [0..3]=O^T d-tiles, [4]=l (ones)
    float m_run = -INFINITY;
    const float scale = 0.125f * 1.44269504f;   // 1/sqrt(D) * log2(e)
    const int kb = sp * KSPAN;
    const int srow = lane >> 3, sg = lane & 7;

    for (int it = 0; it < ITERS; ++it) {
        __syncthreads();                 // prev compute done reading Kt/Vt
#pragma unroll
        for (int half = 0; half < 2; ++half) {
            const int row = wave * 16 + half * 8 + srow;
            const int g = sg ^ (row & 7);
            glds16(Kh + ((size_t)h * S + kb + it * 64 + row) * D + g * 8,
                   &Kt[(wave * 16 + half * 8) * 64]);
            glds16(VhT + ((size_t)h * D + row) * S + kb + it * 64 + g * 8,
                   &Vt[(wave * 16 + half * 8) * 64]);
        }
        __syncthreads();                 // DMA drained

        // scores^T: C[key][q], A = K rows, B = Q frag
        v4f sc[4] = {};
#pragma unroll
        for (int ks = 0; ks < 2; ++ks)
#pragma unroll
            for (int mt = 0; mt < 4; ++mt) {
                const int key = mt * 16 + l16;
                v8h kf = *(const v8h*)&Kt[key * 64 + (((ks * 4 + quad) ^ (key & 7)) * 8)];
                sc[mt] = __builtin_amdgcn_mfma_f32_16x16x32_f16(kf, qf[ks], sc[mt], 0, 0, 0);
            }

        // online softmax for q = l16 (16 in-register scores + 2 shuffles)
        float v = sc[0][0];
#pragma unroll
        for (int mt = 0; mt < 4; ++mt)
#pragma unroll
            for (int r = 0; r < 4; ++r) v = fmaxf(v, sc[mt][r]);
        v = fmaxf(v, __shfl_xor(v, 16));
        v = fmaxf(v, __shfl_xor(v, 32));
        v *= scale;
        const float mnew = fmaxf(m_run, v);
        const float alpha = fexp2(m_run - mnew);   // first iter: exp2(-inf)=0
        m_run = mnew;
#pragma unroll
        for (int i = 0; i < 5; ++i) oc[i] *= alpha;

#pragma unroll
        for (int mt = 0; mt < 4; ++mt) {
            const float p0 = fexp2(fmaf(sc[mt][0], scale, -mnew));
            const float p1 = fexp2(fmaf(sc[mt][1], scale, -mnew));
            const float p2 = fexp2(fmaf(sc[mt][2], scale, -mnew));
            const float p3 = fexp2(fmaf(sc[mt][3], scale, -mnew));
            auto lo = __builtin_amdgcn_cvt_pkrtz(p0, p1);
            auto hi = __builtin_amdgcn_cvt_pkrtz(p2, p3);
            v4h ph; ph[0] = lo[0]; ph[1] = lo[1]; ph[2] = hi[0]; ph[3] = hi[1];
            *(v4h*)&PO.P[wave][l16][mt * 16 + quad * 4] = ph;   // P^T [q][key]
        }
        // Pt is wave-private: in-wave DS ordering suffices (no barrier).

        // PV: O^T += V^T @ P^T (+ ones tile accumulates l)
#pragma unroll
        for (int ks = 0; ks < 2; ++ks) {
            v8h pf = *(const v8h*)&PO.P[wave][l16][ks * 32 + quad * 8];
#pragma unroll
            for (int mt = 0; mt < 5; ++mt) {
                const int dr = mt * 16 + l16;
                v8h vf = *(const v8h*)&Vt[dr * 64 + (((ks * 4 + quad) ^ (dr & 7)) * 8)];
                oc[mt] = __builtin_amdgcn_mfma_f32_16x16x32_f16(vf, pf, oc[mt], 0, 0, 0);
            }
        }
    }

    // epilogue: l from ones tile; normalize; transpose O^T->O via LDS (union)
    const float l = oc[4][0];
    const float invl = 1.f / l;
    __syncthreads();                     // all waves done with PO.P
#pragma unroll
    for (int mt = 0; mt < 4; ++mt) {
        auto lo = __builtin_amdgcn_cvt_pkrtz(oc[mt][0] * invl, oc[mt][1] * invl);
        auto hi = __builtin_amdgcn_cvt_pkrtz(oc[mt][2] * invl, oc[mt][3] * invl);
        v4h oh; oh[0] = lo[0]; oh[1] = lo[1]; oh[2] = hi[0]; oh[3] = hi[1];
        *(v4h*)&PO.O[wave * 16 + l16][mt * 16 + quad * 4] = oh;
    }
    if (quad == 0) {
        float* mlp = ml + (((size_t)sp * H + h) * S + qrow) * 2;
        mlp[0] = m_run;
        mlp[1] = l;
    }
    __syncthreads();
    {
        const int q = t >> 2, dg = (t & 3) * 16;
        v8h o0 = *(const v8h*)&PO.O[q][dg];
        v8h o1 = *(const v8h*)&PO.O[q][dg + 8];
        f16* dst = Opart + (((size_t)sp * H + h) * S + q0 + q) * D + dg;
        *(v8h*)dst = o0;
        *(v8h*)(dst + 8) = o1;
    }
}

// ---------------------------------------------------------------------------
// Kernel 2b: combine 4 splits (m-aware) -> cat[q][h*D+d] fp16. grid = S.
// ---------------------------------------------------------------------------
__global__ void attn_combine(const f16* __restrict__ Opart,
                             const float* __restrict__ ml,
                             f16* __restrict__ cat) {
    const int q = blockIdx.x;
    const int t = threadIdx.x;
#pragma unroll
    for (int i = 0; i < 4; ++i) {
        const int idx = i * 256 + t;          // h*64 + d
        const int h = idx >> 6, d = idx & 63;
        float m[NSPLIT], lv[NSPLIT];
        float M = -INFINITY;
#pragma unroll
        for (int sp = 0; sp < NSPLIT; ++sp) {
            const float* mlp = ml + (((size_t)sp * H + h) * S + q) * 2;
            m[sp] = mlp[0]; lv[sp] = mlp[1];
            M = fmaxf(M, m[sp]);
        }
        float asum = 0.f, o = 0.f;
#pragma unroll
        for (int sp = 0; sp < NSPLIT; ++sp) {
            const float a = fexp2(m[sp] - M) * lv[sp];
            asum += a;
            o += a * (float)Opart[(((size_t)sp * H + h) * S + q) * D + d];
        }
        cat[(size_t)q * E + h * D + d] = (f16)(o / asum);
    }
}

// ---------------------------------------------------------------------------
// Kernel 3: out-proj GEMM (m97 recipe, unchanged). grid (S/64, E/64).
// ---------------------------------------------------------------------------
__global__ __launch_bounds__(256) void gemm_y(
        const f16* __restrict__ cat, const f16* __restrict__ WoB,
        const float* __restrict__ bo, const float* __restrict__ x,
        float* __restrict__ y) {
    const int m0 = blockIdx.x * 64;
    const int n0 = blockIdx.y * 64;
    const int t = threadIdx.x;
    const int wave = t >> 6, lane = t & 63;
    const int quad = lane >> 4, l16 = lane & 15;
    const int wm = wave >> 1, wn = wave & 1;

    __shared__ f16 As[64 * 64];
    __shared__ f16 Bs[64 * 64];

    v4f acc[2][2] = {};
    const int lrow8 = lane >> 3, lg = lane & 7;

    for (int k0 = 0; k0 < E; k0 += 64) {
        __syncthreads();
#pragma unroll
        for (int jj = 0; jj < 2; ++jj) {
            const int j = wave * 2 + jj;
            const int row = j * 8 + lrow8;
            const int g = lg ^ (row & 7);
            glds16(cat + (size_t)(m0 + row) * E + k0 + g * 8, &As[j * 512]);
            glds16(WoB + (size_t)(n0 + row) * E + k0 + g * 8, &Bs[j * 512]);
        }
        __syncthreads();

#pragma unroll
        for (int ks = 0; ks < 2; ++ks) {
            v8h a[2], b[2];
#pragma unroll
            for (int mt = 0; mt < 2; ++mt) {
                const int row = wm * 32 + mt * 16 + l16;
                a[mt] = *(const v8h*)&As[row * 64 + (((ks * 4 + quad) ^ (row & 7)) * 8)];
            }
#pragma unroll
            for (int nt = 0; nt < 2; ++nt) {
                const int row = wn * 32 + nt * 16 + l16;
                b[nt] = *(const v8h*)&Bs[row * 64 + (((ks * 4 + quad) ^ (row & 7)) * 8)];
            }
#pragma unroll
            for (int mt = 0; mt < 2; ++mt)
#pragma unroll
                for (int nt = 0; nt < 2; ++nt)
                    acc[mt][nt] = __builtin_amdgcn_mfma_f32_16x16x32_f16(a[mt], b[nt], acc[mt][nt], 0, 0, 0);
        }
    }

#pragma unroll
    for (int mt = 0; mt < 2; ++mt)
#pragma unroll
        for (int r = 0; r < 4; ++r) {
            const int m = m0 + wm * 32 + mt * 16 + quad * 4 + r;
#pragma unroll
            for (int nt = 0; nt < 2; ++nt) {
                const int e = n0 + wn * 32 + nt * 16 + l16;
                y[(size_t)m * E + e] = acc[mt][nt][r] + bo[e] + x[(size_t)m * E + e];
            }
        }
}

// ---------------------------------------------------------------------------
// Kernel 4: LayerNorm rows of y -> fp32 out. grid = S, block = 256.
// ---------------------------------------------------------------------------
__global__ void ln(const float* __restrict__ y,
                   const float* __restrict__ gamma,
                   const float* __restrict__ beta,
                   float* __restrict__ out) {
    const int s = blockIdx.x;
    const int t = threadIdx.x;
    __shared__ float red[256];

    v4f yv = *(const v4f*)(y + (size_t)s * E + t * 4);
    red[t] = yv[0] + yv[1] + yv[2] + yv[3];
    __syncthreads();
    for (int w = 128; w > 0; w >>= 1) {
        if (t < w) red[t] += red[t + w];
        __syncthreads();
    }
    const float mu = red[0] * (1.f / E);
    __syncthreads();

    float lv = 0.f;
#pragma unroll
    for (int i = 0; i < 4; ++i) { float dd = yv[i] - mu; lv += dd * dd; }
    red[t] = lv;
    __syncthreads();
    for (int w = 128; w > 0; w >>= 1) {
        if (t < w) red[t] += red[t + w];
        __syncthreads();
    }
    const float rstd = rsqrtf(red[0] * (1.f / E) + 1e-5f);

    v4f o;
#pragma unroll
    for (int i = 0; i < 4; ++i) {
        const int e = t * 4 + i;
        o[i] = (yv[i] - mu) * rstd * gamma[e] + beta[e];
    }
    *(v4f*)(out + (size_t)s * E + t * 4) = o;
}

// ---------------------------------------------------------------------------
extern "C" void kernel_launch(void* const* d_in, const int* in_sizes, int n_in,
                              void* d_out, int out_size, void* d_ws, size_t ws_size,
                              hipStream_t stream) {
    const float* x     = (const float*)d_in[0];
    const float* Wk    = (const float*)d_in[1];
    const float* Wq    = (const float*)d_in[2];
    const float* Wv    = (const float*)d_in[3];
    const float* hWk   = (const float*)d_in[4];
    const float* hbk   = (const float*)d_in[5];
    const float* hWv   = (const float*)d_in[6];
    const float* hbv   = (const float*)d_in[7];
    const float* hWq   = (const float*)d_in[8];
    const float* hbq   = (const float*)d_in[9];
    const float* Wo    = (const float*)d_in[10];
    const float* bo    = (const float*)d_in[11];
    const float* gamma = (const float*)d_in[12];
    const float* beta  = (const float*)d_in[13];
    float* out = (float*)d_out;

    // ws layout (MB), no overlap — ws_size is 256 MiB (WRITE_SIZE evidence r10):
    //   Kh @0(4) | Qh @4(4) | VhT @8(4) | Opart @12(16) | ml @28(1)
    //   WoB @29(2) | Xh @31(4) | Wc @35(6) | cat @41(4) | y @45(8)  = 53 MB
    char* base = (char*)d_ws;
    const size_t MB = 1u << 20;
    f16*   Kh    = (f16*)(base);
    f16*   Qh    = (f16*)(base + 4 * MB);
    f16*   VhT   = (f16*)(base + 8 * MB);
    f16*   Opart = (f16*)(base + 12 * MB);
    float* ml    = (float*)(base + 28 * MB);
    f16*   WoB   = (f16*)(base + 29 * MB);
    f16*   Xh    = (f16*)(base + 31 * MB);
    f16*   Wc    = (f16*)(base + 35 * MB);
    f16*   cat   = (f16*)(base + 41 * MB);
    float* y     = (float*)(base + 45 * MB);

    prep<<<3072 + 768, 256, 0, stream>>>(x, Wo, hWk, hWq, hWv, Wk, Wq, Wv,
                                         Xh, WoB, Wc);
    qkv_gemm<<<dim3(S / 128, 3 * H * D / 64), 256, 0, stream>>>(Xh, Wc, hbk, hbq, hbv,
                                                                Kh, Qh, VhT);
    attn_mfma<<<dim3(S / 64, H, NSPLIT), 256, 0, stream>>>(Qh, Kh, VhT, Opart, ml);
    attn_combine<<<S, 256, 0, stream>>>(Opart, ml, cat);
    gemm_y<<<dim3(S / 64, E / 64), 256, 0, stream>>>(cat, WoB, bo, x, y);
    ln<<<S, 256, 0, stream>>>(y, gamma, beta, out);
}